// Round 7
// baseline (1082.298 us; speedup 1.0000x reference)
//
#include <hip/hip_runtime.h>
#include <hip/hip_bf16.h>
#include <math.h>

#define B_ 2
#define L_ 4096
#define D_ 1024
#define H_ 4
#define DK_ 256
#define BL_ 8192
#define C_ 1024
#define NCH_ 128
#define GQP_c 128
#define NS_c 6
#define GIN_c 134
#define GH_c 134

typedef __attribute__((ext_vector_type(8))) short short8;
typedef __attribute__((ext_vector_type(4))) float f32x4;

// ---------------- helpers ----------------
__device__ __forceinline__ float block_sum256(float v, float* red) {
  int t = threadIdx.x;
  #pragma unroll
  for (int o = 32; o > 0; o >>= 1) v += __shfl_down(v, o, 64);
  __syncthreads();
  if ((t & 63) == 0) red[t >> 6] = v;
  __syncthreads();
  return red[0] + red[1] + red[2] + red[3];
}

__device__ __forceinline__ unsigned short bf16bits(float f) {
  __hip_bfloat16 h = __float2bfloat16(f);
  return *(unsigned short*)&h;
}

__device__ __forceinline__ float bits2f(unsigned short u) {
  unsigned int x = ((unsigned int)u) << 16;
  return *(float*)&x;
}

__device__ __forceinline__ float4 fma4(float4 a, float4 b, float4 c) {
  return make_float4(fmaf(a.x, b.x, c.x), fmaf(a.y, b.y, c.y),
                     fmaf(a.z, b.z, c.z), fmaf(a.w, b.w, c.w));
}

__device__ __forceinline__ void gload_lds16(const void* g, void* l) {
  __builtin_amdgcn_global_load_lds(
      (const __attribute__((address_space(1))) void*)g,
      (__attribute__((address_space(3))) void*)l, 16, 0, 0);
}

// ---------------- f32 -> bf16 convert ----------------
__global__ __launch_bounds__(256) void f32_to_bf16_k(const float* __restrict__ in,
    __hip_bfloat16* __restrict__ out) {
  size_t i = ((size_t)blockIdx.x * 256 + threadIdx.x) << 2;
  float4 v = *(const float4*)(in + i);
  ushort4 o;
  o.x = bf16bits(v.x); o.y = bf16bits(v.y); o.z = bf16bits(v.z); o.w = bf16bits(v.w);
  *(ushort4*)((unsigned short*)out + i) = o;
}

// ---------------- transpose W(K,N) f32 -> WT(N,K) bf16 ----------------
__global__ __launch_bounds__(256) void transpose_bf16(const float* __restrict__ W,
    __hip_bfloat16* __restrict__ WT, int K, int N) {
  __shared__ float tile[32][33];
  int t = threadIdx.x;
  int r = t >> 3, c4 = (t & 7) << 2;
  int n0 = blockIdx.x << 5, k0 = blockIdx.y << 5;
  float4 v = *(const float4*)(W + (size_t)(k0 + r) * N + n0 + c4);
  tile[r][c4] = v.x; tile[r][c4 + 1] = v.y; tile[r][c4 + 2] = v.z; tile[r][c4 + 3] = v.w;
  __syncthreads();
  ushort4 o;
  o.x = bf16bits(tile[c4][r]);
  o.y = bf16bits(tile[c4 + 1][r]);
  o.z = bf16bits(tile[c4 + 2][r]);
  o.w = bf16bits(tile[c4 + 3][r]);
  *(ushort4*)((unsigned short*)WT + (size_t)(n0 + r) * K + k0 + c4) = o;
}

// ---------------- small f32 transpose with zero-pad: out[c*OS+r] = in[r*Cc+c] ----------------
__global__ __launch_bounds__(256) void small_transpose(const float* __restrict__ in,
    float* __restrict__ out, int R, int Cc, int OS) {
  int total = Cc * OS;
  for (int e = blockIdx.x * 256 + threadIdx.x; e < total; e += gridDim.x * 256) {
    int cIdx = e / OS, r = e - cIdx * OS;
    out[e] = (r < R) ? in[(size_t)r * Cc + cIdx] : 0.f;
  }
}

// ---------------- Wf1 qg-part -> bf16 BT layout [256 rows][K=128] ----------------
__global__ __launch_bounds__(256) void wf1q_prep(const float* __restrict__ Wf1,
    __hip_bfloat16* __restrict__ out) {
  int idx = blockIdx.x * 256 + threadIdx.x;   // 256*128 = 32768 total
  int u = idx >> 7, i = idx & 127;
  float val = (u < GH_c) ? Wf1[i * GH_c + u] : 0.f;
  out[idx] = __float2bfloat16(val);
}

// ---------------- bf16 MFMA GEMM (m97 structure) ----------------
__global__ __launch_bounds__(256) void gemm_bf16(
    const __hip_bfloat16* __restrict__ A, const __hip_bfloat16* __restrict__ BT,
    const float* __restrict__ bias, float* __restrict__ C, int M, int N, int K) {
  __shared__ __align__(16) __hip_bfloat16 Asm[4096];
  __shared__ __align__(16) __hip_bfloat16 Bsm[4096];
  int tid = threadIdx.x;
  int lane = tid & 63, wave = tid >> 6;
  int wm = wave >> 1, wn = wave & 1;
  int rowBase = blockIdx.y * 128, colBase = blockIdx.x * 128;
  f32x4 acc[4][4];
  #pragma unroll
  for (int i = 0; i < 4; ++i)
    #pragma unroll
    for (int j = 0; j < 4; ++j) acc[i][j] = (f32x4){0.f, 0.f, 0.f, 0.f};

  for (int kt = 0; kt < K; kt += 32) {
    __syncthreads();
    #pragma unroll
    for (int it = 0; it < 2; ++it) {
      int s = tid + (it << 8);
      int T = s >> 6, q = (s >> 4) & 3, m = s & 15;
      const __hip_bfloat16* ga = A + (size_t)(rowBase + T * 16 + m) * K + kt + q * 8;
      gload_lds16(ga, Asm + s * 8);
      const __hip_bfloat16* gb = BT + (size_t)(colBase + T * 16 + m) * K + kt + q * 8;
      gload_lds16(gb, Bsm + s * 8);
    }
    __syncthreads();
    short8 af[4], bfr[4];
    #pragma unroll
    for (int i = 0; i < 4; ++i) {
      af[i]  = *(const short8*)(Asm + ((wm * 4 + i) << 9) + lane * 8);
      bfr[i] = *(const short8*)(Bsm + ((wn * 4 + i) << 9) + lane * 8);
    }
    #pragma unroll
    for (int i = 0; i < 4; ++i)
      #pragma unroll
      for (int j = 0; j < 4; ++j)
        acc[i][j] = __builtin_amdgcn_mfma_f32_16x16x32_bf16(af[i], bfr[j], acc[i][j], 0, 0, 0);
  }
  int r0 = (lane >> 4) * 4, c0 = lane & 15;
  #pragma unroll
  for (int i = 0; i < 4; ++i) {
    int row = rowBase + (wm * 4 + i) * 16 + r0;
    #pragma unroll
    for (int j = 0; j < 4; ++j) {
      int col = colBase + (wn * 4 + j) * 16 + c0;
      float bs = bias ? bias[col] : 0.f;
      #pragma unroll
      for (int r = 0; r < 4; ++r)
        C[(size_t)(row + r) * N + col] = acc[i][j][r] + bs;
    }
  }
}

// ---------------- depthwise causal conv (K=4) + SiLU ----------------
__global__ __launch_bounds__(256) void conv_silu(const float* __restrict__ in,
    const float* __restrict__ w, float* __restrict__ out) {
  int idx = blockIdx.x * 256 + threadIdx.x;
  int c = idx & (C_ - 1);
  int l = (idx >> 10) & (L_ - 1);
  float acc = 0.f;
  #pragma unroll
  for (int j = 0; j < 4; ++j) {
    int ll = l - 3 + j;
    if (ll >= 0) acc += w[(c << 2) + j] * in[idx + ((j - 3) << 10)];
  }
  out[idx] = acc / (1.f + expf(-acc));
}

// ---------------- beta = sigmoid(x @ Wb) ----------------
__global__ __launch_bounds__(256) void beta_kernel(const float* __restrict__ x,
    const float* __restrict__ Wb, float* __restrict__ beta) {
  int row = blockIdx.x;
  int t = threadIdx.x;
  int h = t >> 6, lane = t & 63;
  const float* xr = x + (size_t)row * D_;
  float acc = 0.f;
  for (int k = lane; k < D_; k += 64) acc += xr[k] * Wb[(k << 2) + h];
  #pragma unroll
  for (int o = 32; o > 0; o >>= 1) acc += __shfl_down(acc, o, 64);
  if (lane == 0) beta[(row << 2) + h] = 1.f / (1.f + expf(-acc));
}

// ---------------- l2norm q,k; v*beta; kb; transpose BLHD -> BHLD ----------------
__global__ __launch_bounds__(256) void precompute(const float* __restrict__ q,
    const float* __restrict__ k, const float* __restrict__ v,
    const float* __restrict__ beta,
    float* __restrict__ qn, float* __restrict__ kn,
    float* __restrict__ vb, float* __restrict__ kb) {
  __shared__ float red[4];
  int bid = blockIdx.x;
  int t = threadIdx.x;
  int b = bid >> 14;
  int h = (bid >> 12) & 3;
  int l = bid & (L_ - 1);
  size_t in_off = (((size_t)(b * L_ + l)) << 10) + (h << 8) + t;
  float qv = q[in_off], kv = k[in_off], vv = v[in_off];
  float sq = block_sum256(qv * qv, red);
  float sk = block_sum256(kv * kv, red);
  float rq = rsqrtf(sq + 1e-6f);
  float rk = rsqrtf(sk + 1e-6f);
  float bt = beta[((b * L_ + l) << 2) + h];
  size_t oo = ((size_t)bid << 8) + t;
  float knv = kv * rk;
  qn[oo] = qv * rq;
  kn[oo] = knv;
  vb[oo] = vv * bt;
  kb[oo] = knv * bt;
}

// ---------------- per-chunk: inv (fwd-subst, bf16-rounded) + attn + knT + qn_bf ----------------
__global__ __launch_bounds__(256) void inv_attn(const float* __restrict__ qn,
    const float* kn, const float* __restrict__ kb,
    float* __restrict__ invb, __hip_bfloat16* __restrict__ att_bf,
    __hip_bfloat16* knT_bf) {
  __shared__ float kn_s[32][257];
  __shared__ float inv_s[32][33];
  int ci = blockIdx.x;
  int t = threadIdx.x;
  size_t base = ((size_t)ci) << 13;
  for (int e = t; e < 8192; e += 256) kn_s[e >> 8][e & 255] = kn[base + e];
  __syncthreads();
  {
    unsigned short tmp[32];
    #pragma unroll
    for (int j = 0; j < 32; ++j) tmp[j] = bf16bits(kn_s[j][t]);
    unsigned short* kd = (unsigned short*)knT_bf + (((size_t)ci) << 14) +
                         (size_t)(t >> 4) * 512 + (size_t)(t & 15) * 8;
    #pragma unroll
    for (int g = 0; g < 4; ++g) *(uint4*)(kd + g * 128) = ((const uint4*)tmp)[g];
  }
  {
    int r = t >> 3, kt = t & 7;
    const float4* qrow = (const float4*)(qn + base + (size_t)r * 256 + (kt << 5));
    unsigned short tmp[32];
    #pragma unroll
    for (int i = 0; i < 8; ++i) {
      float4 f = qrow[i];
      tmp[i * 4 + 0] = bf16bits(f.x); tmp[i * 4 + 1] = bf16bits(f.y);
      tmp[i * 4 + 2] = bf16bits(f.z); tmp[i * 4 + 3] = bf16bits(f.w);
    }
    unsigned short* qd = (unsigned short*)knT_bf + (((size_t)ci) << 14) + 8192 +
                         (size_t)(((r >> 4) << 3) + kt) * 512 + (size_t)(r & 15) * 8;
    #pragma unroll
    for (int g = 0; g < 4; ++g) *(uint4*)(qd + g * 128) = ((const uint4*)tmp)[g];
  }
  #pragma unroll
  for (int p = 0; p < 4; ++p) {
    int e = t + (p << 8);
    int i = e >> 5, j = e & 31;
    const float* kbi = kb + base + (i << 8);
    const float* qni = qn + base + (i << 8);
    float am = 0.f, aa = 0.f;
    for (int kk = 0; kk < 256; ++kk) {
      float knv = kn_s[j][kk];
      am += kbi[kk] * knv;
      aa += qni[kk] * knv;
    }
    inv_s[i][j] = (j < i) ? -am : 0.f;
    ((unsigned short*)att_bf)[((size_t)ci << 10) + (size_t)(i >> 4) * 512 +
        (size_t)((i & 15) + ((j >> 3) << 4)) * 8 + (j & 7)] =
        bf16bits((j <= i) ? aa : 0.f);
  }
  __syncthreads();
  for (int i = 1; i < 32; ++i) {
    float upd = 0.f;
    if (t < i) {
      for (int kk = t + 1; kk < i; ++kk) upd += inv_s[i][kk] * inv_s[kk][t];
    }
    __syncthreads();
    if (t < i) inv_s[i][t] += upd;
    __syncthreads();
  }
  #pragma unroll
  for (int p = 0; p < 4; ++p) {
    int e = t + (p << 8);
    int i = e >> 5, j = e & 31;
    float val = inv_s[i][j] + (i == j ? 1.f : 0.f);
    val = __bfloat162float(__float2bfloat16(val));
    invb[((size_t)ci << 10) + e] = val;
  }
}

// ---------------- u = inv@vb (in place f32); w = -(inv@kb) as bf16 frag-order ----------------
__global__ __launch_bounds__(256) void uw_kernel(const float* __restrict__ invb,
    float* __restrict__ vb_u, float* kb_w, __hip_bfloat16* w_bf) {
  __shared__ float inv_s[32][33];
  __shared__ float tile[32][260];
  int ci = blockIdx.x, t = threadIdx.x;
  size_t base = ((size_t)ci) << 13;
  for (int e = t; e < 1024; e += 256) inv_s[e >> 5][e & 31] = invb[((size_t)ci << 10) + e];
  for (int ph = 0; ph < 2; ++ph) {
    const float* src = (ph == 0) ? vb_u : kb_w;
    __syncthreads();
    for (int f = t; f < 2048; f += 256) {
      int e = f << 2;
      *(float4*)&tile[e >> 8][e & 255] = *(const float4*)(src + base + e);
    }
    __syncthreads();
    int c4 = (t & 63) << 2;
    int ig = t >> 6;
    float4 acc[8];
    #pragma unroll
    for (int ii = 0; ii < 8; ++ii) acc[ii] = make_float4(0.f, 0.f, 0.f, 0.f);
    for (int j = 0; j < 32; ++j) {
      float4 v4 = *(const float4*)&tile[j][c4];
      #pragma unroll
      for (int ii = 0; ii < 8; ++ii) {
        float iv = inv_s[(ig << 3) + ii][j];
        acc[ii].x += iv * v4.x; acc[ii].y += iv * v4.y;
        acc[ii].z += iv * v4.z; acc[ii].w += iv * v4.w;
      }
    }
    #pragma unroll
    for (int ii = 0; ii < 8; ++ii) {
      int i = (ig << 3) + ii;
      if (ph == 0) {
        *(float4*)(vb_u + base + (i << 8) + c4) = acc[ii];
      } else {
        ushort4 o;
        o.x = bf16bits(-acc[ii].x); o.y = bf16bits(-acc[ii].y);
        o.z = bf16bits(-acc[ii].z); o.w = bf16bits(-acc[ii].w);
        unsigned short* wd = (unsigned short*)w_bf + (((size_t)ci) << 14) +
            (size_t)(((i >> 4) << 3) + (c4 >> 5)) * 512 +
            (size_t)((i & 15) + (((c4 >> 3) & 3) << 4)) * 8 + (c4 & 7);
        *(ushort4*)wd = o;
      }
    }
  }
}

// ---------------- hybrid producer/consumer MFMA scan ----------------
// grid = 128 blocks x 128 threads (2 waves): bh = blockIdx&7, cb = blockIdx>>3.
// wave1 = PRODUCER: stages ONLY K+A for the next chunk (18 gload_lds) into a
//   double buffer + asm vmcnt(0) + RAW s_barrier (no implicit waitcnt -> the
//   consumer is never drained; r6's __syncthreads drain was the regression).
// wave0 = CONSUMER: W/Q/u register-direct (r4's win; dropping K+A from the
//   register set cuts peak demand ~280->~220 VGPR so the prefetch can stay
//   resident), pinned early with sched_barrier(0). Issues NO global_load_lds
//   -> its ds_reads get no forced vmcnt drain (round-1 failure impossible).
// Protocol: producer writes buf[(nc+1)&1] while consumer reads buf[nc&1];
// consumer's LDS reads complete before its barrier (all uses precede it).
// Math/numerics identical to rounds 4/6.
__global__ __launch_bounds__(128, 1) void scan_kernel(
    const __hip_bfloat16* __restrict__ w_bf,
    const __hip_bfloat16* __restrict__ kq_bf,   // per chunk: [0,8192)=knT frag, [8192,16384)=qn frag
    const __hip_bfloat16* __restrict__ att_bf,  // per chunk 1024 shorts frag-order
    const float* __restrict__ u, float* __restrict__ dout) {
  // stg per buffer (shorts): K[0,8192) A[8192,9216)
  __shared__ __align__(16) unsigned short stg[2][9216];
  __shared__ __align__(16) unsigned short Shi[16 * 264];
  __shared__ __align__(16) unsigned short Slo[16 * 264];
  __shared__ __align__(16) float UtT[16 * 36];
  int tid = threadIdx.x;
  int wave = tid >> 6, lane = tid & 63;
  int mlane = lane & 15, quad = lane >> 4;
  int bh = blockIdx.x & 7;
  int cb = blockIdx.x >> 3;
  int cbase = cb << 4;

  const unsigned short* wbase = (const unsigned short*)w_bf;
  const unsigned short* kqbase = (const unsigned short*)kq_bf;
  const unsigned short* abase = (const unsigned short*)att_bf;

  if (wave == 1) {
    // -------- producer --------
    auto stage_chunk = [&](int nc, int buf) {
      size_t ci = (size_t)(bh * NCH_ + nc);
      const unsigned short* kg = kqbase + (ci << 14) + lane * 8;
      const unsigned short* ag = abase + (ci << 10) + lane * 8;
      unsigned short* l = &stg[buf][lane * 8];
      #pragma unroll
      for (int s = 0; s < 16; ++s) gload_lds16(kg + s * 512, l + s * 512);
      gload_lds16(ag, l + 8192);
      gload_lds16(ag + 512, l + 8704);
    };
    stage_chunk(0, 0);
    asm volatile("s_waitcnt vmcnt(0)" ::: "memory");
    asm volatile("s_barrier" ::: "memory");          // B0: buf0 ready
    for (int nc = 0; nc < NCH_; ++nc) {
      if (nc + 1 < NCH_) {
        stage_chunk(nc + 1, (nc + 1) & 1);
        asm volatile("s_waitcnt vmcnt(0)" ::: "memory");
      }
      asm volatile("s_barrier" ::: "memory");        // Bn: next buf ready
    }
    return;
  }

  // -------- consumer (wave 0) --------
  short8 Wr[16], Qr[16];
  float ur[8], urn[8];
  auto load_WQ = [&](int nc) {
    size_t cb14 = ((size_t)(bh * NCH_ + nc)) << 14;
    const short8* wg = (const short8*)(wbase + cb14 + (size_t)lane * 8);
    const short8* qg = (const short8*)(kqbase + cb14 + 8192 + (size_t)lane * 8);
    #pragma unroll
    for (int s = 0; s < 16; ++s) { Wr[s] = wg[s * 64]; Qr[s] = qg[s * 64]; }
  };
  auto load_u8 = [&](int nc, float* dst) {
    size_t cbf = ((size_t)(bh * NCH_ + nc)) << 13;
    const float* up = u + cbf + (size_t)(quad * 4) * 256 + cbase + mlane;
    #pragma unroll
    for (int tt = 0; tt < 2; ++tt)
      #pragma unroll
      for (int r = 0; r < 4; ++r) dst[tt * 4 + r] = up[(tt * 16 + r) * 256];
  };

  for (int e = lane; e < 16 * 264; e += 64) { Shi[e] = 0; Slo[e] = 0; }
  f32x4 accS[16];
  #pragma unroll
  for (int i = 0; i < 16; ++i) accS[i] = (f32x4){0.f, 0.f, 0.f, 0.f};
  load_WQ(0);
  load_u8(0, ur);
  asm volatile("s_barrier" ::: "memory");            // matches producer B0

  for (int nc = 0; nc < NCH_; ++nc) {
    int cur = nc & 1;
    int nn = nc + 1 < NCH_ ? nc + 1 : NCH_ - 1;
    const unsigned short* SK = &stg[cur][0];
    const unsigned short* SA = &stg[cur][8192];
    // hoist attn fragments (hide LDS latency under phase 1)
    short8 a0 = *(const short8*)&SA[lane * 8];
    short8 a1 = *(const short8*)&SA[512 + lane * 8];

    // phase 1: ut = u + (-w)@S ; o-partial = q@S  (8 independent chains)
    f32x4 uh0 = (f32x4){ur[0], ur[1], ur[2], ur[3]};
    f32x4 uh1 = (f32x4){ur[4], ur[5], ur[6], ur[7]};
    f32x4 ul0 = (f32x4){0.f, 0.f, 0.f, 0.f}, ul1 = (f32x4){0.f, 0.f, 0.f, 0.f};
    f32x4 oh0 = (f32x4){0.f, 0.f, 0.f, 0.f}, oh1 = (f32x4){0.f, 0.f, 0.f, 0.f};
    f32x4 ol0 = (f32x4){0.f, 0.f, 0.f, 0.f}, ol1 = (f32x4){0.f, 0.f, 0.f, 0.f};
    #pragma unroll
    for (int kt = 0; kt < 8; ++kt) {
      short8 bhi = *(const short8*)&Shi[mlane * 264 + kt * 32 + quad * 8];
      short8 blo = *(const short8*)&Slo[mlane * 264 + kt * 32 + quad * 8];
      uh0 = __builtin_amdgcn_mfma_f32_16x16x32_bf16(Wr[kt], bhi, uh0, 0, 0, 0);
      ul0 = __builtin_amdgcn_mfma_f32_16x16x32_bf16(Wr[kt], blo, ul0, 0, 0, 0);
      uh1 = __builtin_amdgcn_mfma_f32_16x16x32_bf16(Wr[8 + kt], bhi, uh1, 0, 0, 0);
      ul1 = __builtin_amdgcn_mfma_f32_16x16x32_bf16(Wr[8 + kt], blo, ul1, 0, 0, 0);
      oh0 = __builtin_amdgcn_mfma_f32_16x16x32_bf16(Qr[kt], bhi, oh0, 0, 0, 0);
      ol0 = __builtin_amdgcn_mfma_f32_16x16x32_bf16(Qr[kt], blo, ol0, 0, 0, 0);
      oh1 = __builtin_amdgcn_mfma_f32_16x16x32_bf16(Qr[8 + kt], bhi, oh1, 0, 0, 0);
      ol1 = __builtin_amdgcn_mfma_f32_16x16x32_bf16(Qr[8 + kt], blo, ol1, 0, 0, 0);
    }
    f32x4 ut0 = uh0 + ul0, ut1 = uh1 + ul1;
    // same-wave LDS relayout (C-layout -> transposed image -> B-frag)
    *(f32x4*)&UtT[mlane * 36 + quad * 4] = ut0;
    *(f32x4*)&UtT[mlane * 36 + 16 + quad * 4] = ut1;
    // prefetch next chunk's W/Q/u; Wr/Qr/ur dead after phase 1. Pin the
    // issue point so the scheduler can't sink these to their uses.
    load_WQ(nn);
    load_u8(nn, urn);
    __builtin_amdgcn_sched_barrier(0);
    short8 but;
    {
      const float* up = &UtT[mlane * 36 + quad * 8];
      #pragma unroll
      for (int j = 0; j < 8; ++j) but[j] = (short)bf16bits(up[j]);
    }
    // phase 2: o = q@S + attn@ut -> store
    f32x4 o0 = oh0 + ol0, o1 = oh1 + ol1;
    o0 = __builtin_amdgcn_mfma_f32_16x16x32_bf16(a0, but, o0, 0, 0, 0);
    o1 = __builtin_amdgcn_mfma_f32_16x16x32_bf16(a1, but, o1, 0, 0, 0);
    size_t cbf = ((size_t)(bh * NCH_ + nc)) << 13;
    float* op = dout + cbf + (size_t)(quad * 4) * 256 + cbase + mlane;
    #pragma unroll
    for (int r = 0; r < 4; ++r) { op[r * 256] = o0[r]; op[(16 + r) * 256] = o1[r]; }
    // phase 3: S += knT @ ut (f32 regs), write bf16 hi/lo image in place
    #pragma unroll
    for (int t2 = 0; t2 < 16; ++t2) {
      short8 kA = *(const short8*)&SK[t2 * 512 + lane * 8];
      accS[t2] = __builtin_amdgcn_mfma_f32_16x16x32_bf16(kA, but, accS[t2], 0, 0, 0);
      unsigned short nh[4], nl[4];
      #pragma unroll
      for (int r = 0; r < 4; ++r) {
        float sv = accS[t2][r];
        unsigned short hb = bf16bits(sv);
        nh[r] = hb;
        nl[r] = bf16bits(sv - bits2f(hb));
      }
      *(uint2*)&Shi[mlane * 264 + t2 * 16 + quad * 4] = *(const uint2*)nh;
      *(uint2*)&Slo[mlane * 264 + t2 * 16 + quad * 4] = *(const uint2*)nl;
    }
    #pragma unroll
    for (int r = 0; r < 8; ++r) ur[r] = urn[r];
    asm volatile("s_barrier" ::: "memory");          // matches producer Bn
  }
}

// ---------------- gate: NL=8 tokens/block; shared qg-matvec hoisted to qgH GEMM ----------------
__global__ __launch_bounds__(256, 1) void gate_kernel(
    const float* __restrict__ v, const float* __restrict__ delta,
    const float* __restrict__ qgH,
    const float* __restrict__ fw0, const float* __restrict__ fw1T,
    const float* __restrict__ fw2T, const float* __restrict__ fw3T,
    const float* __restrict__ Wf1, const float* __restrict__ Wf2,
    const float* __restrict__ bf1, const float* __restrict__ bf2,
    const float* __restrict__ ltm, const float* __restrict__ onw,
    __hip_bfloat16* __restrict__ obf) {
  __shared__ float W1t[6][136];   // Wf1 rows 128..133 (summary tail)
  __shared__ float W2f[804];      // Wf2 [134][6] flat
  __shared__ float bf1s[136];
  int t = threadIdx.x;
  int wave = t >> 6, lane = t & 63;
  for (int e = t; e < 804; e += 256) {
    int s = e / 134, u = e - s * 134;
    W1t[s][u] = Wf1[(128 + s) * GH_c + u];
    W2f[e] = Wf2[e];
  }
  if (t < GH_c) bf1s[t] = bf1[t];
  __syncthreads();

  int bid = blockIdx.x;
  int bl0 = (((bid & 7) << 7) | (bid >> 3)) << 3;   // 1024 blocks -> 8 tokens each
  int b = bl0 >> 12;
  int h = wave;
  int c = (h << 8) + (lane << 2);

  float4 fw3r[15], fw2r[7], fw1r[3], fw0r;
  #pragma unroll
  for (int j = 0; j < 15; ++j) fw3r[j] = *(const float4*)(fw3T + (j << 10) + c);
  #pragma unroll
  for (int j = 0; j < 7; ++j) fw2r[j] = *(const float4*)(fw2T + (j << 10) + c);
  #pragma unroll
  for (int j = 0; j < 3; ++j) fw1r[j] = *(const float4*)(fw1T + (j << 10) + c);
  fw0r = *(const float4*)(fw0 + c);
  float4 ow = *(const float4*)(onw + (lane << 2));
  float itemp = expf(ltm[h]);
  float b2r[6];
  #pragma unroll
  for (int s = 0; s < 6; ++s) b2r[s] = bf2[s];
  int u3 = 128 + (lane < 6 ? lane : 0);

  auto gelu = [](float a) -> float {
    return 0.5f * a * (1.f + erff(a * 0.70710678f));
  };

  for (int tk = 0; tk < 8; ++tk) {
    int bl = bl0 + tk;
    int l = bl & (L_ - 1);
    float4 st0, st1, st2, st3, st4, st5;
    st1 = make_float4(0, 0, 0, 0);
    st2 = make_float4(0, 0, 0, 0);
    st3 = make_float4(0, 0, 0, 0);
    #pragma unroll
    for (int j = 0; j < 15; ++j) {
      int ll = l - 14 + j;
      float4 vj = make_float4(0, 0, 0, 0);
      if (ll >= 0) vj = *(const float4*)(v + ((((size_t)(b * L_ + ll)) << 10) + c));
      st3 = fma4(fw3r[j], vj, st3);
      if (j >= 8) st2 = fma4(fw2r[j - 8], vj, st2);
      if (j >= 12) st1 = fma4(fw1r[j - 12], vj, st1);
      if (j == 14) {
        st0 = make_float4(fw0r.x * vj.x, fw0r.y * vj.y, fw0r.z * vj.z, fw0r.w * vj.w);
        st5 = vj;
      }
    }
    st4 = *(const float4*)(delta + ((((size_t)((b * H_ + h) * L_ + l)) << 8) + (lane << 2)));

    float s0 = st0.x + st0.y + st0.z + st0.w;
    float s1 = st1.x + st1.y + st1.z + st1.w;
    float s2 = st2.x + st2.y + st2.z + st2.w;
    float s3 = st3.x + st3.y + st3.z + st3.w;
    float s4 = st4.x + st4.y + st4.z + st4.w;
    float s5 = st5.x + st5.y + st5.z + st5.w;
    #pragma unroll
    for (int o = 32; o > 0; o >>= 1) {
      s0 += __shfl_down(s0, o, 64); s1 += __shfl_down(s1, o, 64);
      s2 += __shfl_down(s2, o, 64); s3 += __shfl_down(s3, o, 64);
      s4 += __shfl_down(s4, o, 64); s5 += __shfl_down(s5, o, 64);
    }
    float ss_[6];
    ss_[0] = __shfl(s0, 0, 64) * (1.f / 256.f);
    ss_[1] = __shfl(s1, 0, 64) * (1.f / 256.f);
    ss_[2] = __shfl(s2, 0, 64) * (1.f / 256.f);
    ss_[3] = __shfl(s3, 0, 64) * (1.f / 256.f);
    ss_[4] = __shfl(s4, 0, 64) * (1.f / 256.f);
    ss_[5] = __shfl(s5, 0, 64) * (1.f / 256.f);

    const float* qr = qgH + ((size_t)bl << 8);
    float a0 = qr[lane] + bf1s[lane];
    float a1 = qr[64 + lane] + bf1s[64 + lane];
    float a2 = qr[u3] + bf1s[u3];
    #pragma unroll
    for (int s = 0; s < 6; ++s) {
      a0 = fmaf(W1t[s][lane], ss_[s], a0);
      a1 = fmaf(W1t[s][64 + lane], ss_[s], a1);
      a2 = fmaf(W1t[s][u3], ss_[s], a2);
    }
    float h0 = gelu(a0);
    float h1 = gelu(a1);
    float h2 = (lane < 6) ? gelu(a2) : 0.f;

    const float* w2a = W2f + lane * 6;
    const float* w2b = W2f + (64 + lane) * 6;
    const float* w2c = W2f + u3 * 6;
    float t0 = h0 * w2a[0] + h1 * w2b[0] + h2 * w2c[0];
    float t1 = h0 * w2a[1] + h1 * w2b[1] + h2 * w2c[1];
    float t2 = h0 * w2a[2] + h1 * w2b[2] + h2 * w2c[2];
    float t3 = h0 * w2a[3] + h1 * w2b[3] + h2 * w2c[3];
    float t4 = h0 * w2a[4] + h1 * w2b[4] + h2 * w2c[4];
    float t5 = h0 * w2a[5] + h1 * w2b[5] + h2 * w2c[5];
    #pragma unroll
    for (int o = 32; o > 0; o >>= 1) {
      t0 += __shfl_down(t0, o, 64); t1 += __shfl_down(t1, o, 64);
      t2 += __shfl_down(t2, o, 64); t3 += __shfl_down(t3, o, 64);
      t4 += __shfl_down(t4, o, 64); t5 += __shfl_down(t5, o, 64);
    }
    float p0, p1, p2, p3, p4, p5;
    if (lane == 0) {
      float l0v = (t0 + b2r[0]) / itemp, l1v = (t1 + b2r[1]) / itemp;
      float l2v = (t2 + b2r[2]) / itemp, l3v = (t3 + b2r[3]) / itemp;
      float l4v = (t4 + b2r[4]) / itemp, l5v = (t5 + b2r[5]) / itemp;
      float m = fmaxf(fmaxf(fmaxf(l0v, l1v), fmaxf(l2v, l3v)), fmaxf(l4v, l5v));
      float e0 = expf(l0v - m), e1 = expf(l1v - m), e2 = expf(l2v - m);
      float e3 = expf(l3v - m), e4 = expf(l4v - m), e5 = expf(l5v - m);
      float inv = 1.f / (e0 + e1 + e2 + e3 + e4 + e5);
      p0 = e0 * inv * 0.88f + 0.02f; p1 = e1 * inv * 0.88f + 0.02f;
      p2 = e2 * inv * 0.88f + 0.02f; p3 = e3 * inv * 0.88f + 0.02f;
      p4 = e4 * inv * 0.88f + 0.02f; p5 = e5 * inv * 0.88f + 0.02f;
    }
    p0 = __shfl(p0, 0, 64); p1 = __shfl(p1, 0, 64); p2 = __shfl(p2, 0, 64);
    p3 = __shfl(p3, 0, 64); p4 = __shfl(p4, 0, 64); p5 = __shfl(p5, 0, 64);

    float4 fu;
    fu.x = p0 * st0.x + p1 * st1.x + p2 * st2.x + p3 * st3.x + p4 * st4.x + p5 * st5.x;
    fu.y = p0 * st0.y + p1 * st1.y + p2 * st2.y + p3 * st3.y + p4 * st4.y + p5 * st5.y;
    fu.z = p0 * st0.z + p1 * st1.z + p2 * st2.z + p3 * st3.z + p4 * st4.z + p5 * st5.z;
    fu.w = p0 * st0.w + p1 * st1.w + p2 * st2.w + p3 * st3.w + p4 * st4.w + p5 * st5.w;
    float ssq = fu.x * fu.x + fu.y * fu.y + fu.z * fu.z + fu.w * fu.w;
    #pragma unroll
    for (int o = 32; o > 0; o >>= 1) ssq += __shfl_xor(ssq, o, 64);
    float sc = rsqrtf(ssq * (1.f / 256.f) + 1e-5f);
    ushort4 ob;
    ob.x = bf16bits(fu.x * sc * ow.x);
    ob.y = bf16bits(fu.y * sc * ow.y);
    ob.z = bf16bits(fu.z * sc * ow.z);
    ob.w = bf16bits(fu.w * sc * ow.w);
    *(ushort4*)((unsigned short*)obf + (((size_t)bl) << 10) + c) = ob;
  }
}

// ---------------- launch ----------------
extern "C" void kernel_launch(void* const* d_in, const int* in_sizes, int n_in,
                              void* d_out, int out_size, void* d_ws, size_t ws_size,
                              hipStream_t stream) {
  const float* x   = (const float*)d_in[0];
  const float* Wq  = (const float*)d_in[1];
  const float* Wk  = (const float*)d_in[2];
  const float* Wv  = (const float*)d_in[3];
  const float* Wb  = (const float*)d_in[4];
  const float* cqw = (const float*)d_in[5];
  const float* ckw = (const float*)d_in[6];
  const float* cvw = (const float*)d_in[7];
  const float* fw0 = (const float*)d_in[8];
  const float* fw1 = (const float*)d_in[9];
  const float* fw2 = (const float*)d_in[10];
  const float* fw3 = (const float*)d_in[11];
  const float* Wqg = (const float*)d_in[12];
  const float* bqg = (const float*)d_in[13];
  const float* Wf1 = (const float*)d_in[14];
  const float* bf1 = (const float*)d_in[15];
  const float* Wf2 = (const float*)d_in[16];
  const float* bf2 = (const float*)d_in[17];
  const float* ltm = (const float*)d_in[18];
  const float* onw = (const float*)d_in[19];
  const float* Wo  = (const float*)d_in[20];
  float* out = (float*)d_out;
  float* ws = (float*)d_ws;

  const size_t BIG = (size_t)BL_ * C_;
  float* qpre = ws;                 // -> qn f32 -> gate_bf after scan
  float* kpre = ws + BIG;           // -> kn f32 -> knT_bf+qn_bf (frag-order, in-place)
  float* vpre = ws + 2 * BIG;       // -> vb -> u f32
  float* qs   = ws + 3 * BIG;       // x_bf early -> conv q -> delta_out
  float* ks   = ws + 4 * BIG;       // conv k (scratch) -> qgH/qg_bf/wf1qT after precompute
  float* vs   = ws + 5 * BIG;       // conv v (FIR/v_direct)
  float* kbw  = ws + 6 * BIG;       // wT bf16 early -> kb -> w_bf (frag-order) -> woT
  float* invb = ws + 7 * BIG;
  float* attb = invb + (size_t)1024 * 1024;
  float* beta = attb + (size_t)1024 * 1024;
  float* qg   = beta + (size_t)BL_ * H_;

  __hip_bfloat16* x_bf  = (__hip_bfloat16*)qs;
  __hip_bfloat16* wqT   = (__hip_bfloat16*)kbw;
  __hip_bfloat16* wkT   = wqT + (size_t)1024 * 1024;
  __hip_bfloat16* wvT   = wkT + (size_t)1024 * 1024;
  __hip_bfloat16* wqgT  = wvT + (size_t)1024 * 1024;
  __hip_bfloat16* woT   = (__hip_bfloat16*)kbw;
  __hip_bfloat16* gate_bf = (__hip_bfloat16*)qpre;
  __hip_bfloat16* knT_bf = (__hip_bfloat16*)kpre;   // + qn_bf in slot second halves
  __hip_bfloat16* w_bf   = (__hip_bfloat16*)kbw;
  __hip_bfloat16* att_bf = (__hip_bfloat16*)attb;
  float* scr   = attb + (size_t)600000;
  float* fw1T  = scr;
  float* fw2T  = scr + 3072;
  float* fw3T  = scr + 10240;

  float* qgH = ks;                                            // 8192 x 256 f32
  __hip_bfloat16* qg_bf  = (__hip_bfloat16*)(ks + (size_t)3 * 1024 * 1024);
  __hip_bfloat16* wf1qT  = (__hip_bfloat16*)(ks + (size_t)4 * 1024 * 1024);

  dim3 blk(256);
  f32_to_bf16_k<<<dim3(BL_ * D_ / 1024), blk, 0, stream>>>(x, x_bf);
  transpose_bf16<<<dim3(32, 32), blk, 0, stream>>>(Wq, wqT, D_, C_);
  transpose_bf16<<<dim3(32, 32), blk, 0, stream>>>(Wk, wkT, D_, C_);
  transpose_bf16<<<dim3(32, 32), blk, 0, stream>>>(Wv, wvT, D_, C_);
  transpose_bf16<<<dim3(4, 32), blk, 0, stream>>>(Wqg, wqgT, D_, GQP_c);
  small_transpose<<<dim3(16), blk, 0, stream>>>(fw1, fw1T, 1024, 3, 1024);
  small_transpose<<<dim3(32), blk, 0, stream>>>(fw2, fw2T, 1024, 7, 1024);
  small_transpose<<<dim3(64), blk, 0, stream>>>(fw3, fw3T, 1024, 15, 1024);
  gemm_bf16<<<dim3(8, 64), blk, 0, stream>>>(x_bf, wqT, nullptr, qpre, BL_, C_, D_);
  gemm_bf16<<<dim3(8, 64), blk, 0, stream>>>(x_bf, wkT, nullptr, kpre, BL_, C_, D_);
  gemm_bf16<<<dim3(8, 64), blk, 0, stream>>>(x_bf, wvT, nullptr, vpre, BL_, C_, D_);
  gemm_bf16<<<dim3(1, 64), blk, 0, stream>>>(x_bf, wqgT, bqg, qg, BL_, GQP_c, D_);
  beta_kernel<<<dim3(BL_), blk, 0, stream>>>(x, Wb, beta);
  conv_silu<<<dim3(BL_ * C_ / 256), blk, 0, stream>>>(qpre, cqw, qs);
  conv_silu<<<dim3(BL_ * C_ / 256), blk, 0, stream>>>(kpre, ckw, ks);
  conv_silu<<<dim3(BL_ * C_ / 256), blk, 0, stream>>>(vpre, cvw, vs);
  precompute<<<dim3(B_ * H_ * L_), blk, 0, stream>>>(qs, ks, vs, beta, qpre, kpre,
                                                     vpre, kbw);
  // ks slot now free: build qgH = qg @ Wf1[0:128,:] (bf16 MFMA, f32 accum)
  f32_to_bf16_k<<<dim3(BL_ * GQP_c / 1024), blk, 0, stream>>>(qg, qg_bf);
  wf1q_prep<<<dim3(128), blk, 0, stream>>>(Wf1, wf1qT);
  gemm_bf16<<<dim3(2, 64), blk, 0, stream>>>(qg_bf, wf1qT, nullptr, qgH, BL_, 256, 128);
  inv_attn<<<dim3(1024), blk, 0, stream>>>(qpre, kpre, kbw, invb, att_bf, knT_bf);
  uw_kernel<<<dim3(1024), blk, 0, stream>>>(invb, vpre, kbw, w_bf);
  scan_kernel<<<dim3(128), dim3(128), 0, stream>>>(w_bf, knT_bf, att_bf, vpre, qs);
  transpose_bf16<<<dim3(32, 32), blk, 0, stream>>>(Wo, woT, C_, D_);
  gate_kernel<<<dim3(1024), blk, 0, stream>>>(vs, qs, qgH, fw0, fw1T, fw2T, fw3T,
                                              Wf1, Wf2, bf1, bf2, ltm, onw, gate_bf);
  gemm_bf16<<<dim3(8, 64), blk, 0, stream>>>(gate_bf, woT, nullptr, out, BL_, D_, C_);
}

// Round 8
// 943.818 us; speedup vs baseline: 1.1467x; 1.1467x over previous
//
#include <hip/hip_runtime.h>
#include <hip/hip_bf16.h>
#include <math.h>

#define B_ 2
#define L_ 4096
#define D_ 1024
#define H_ 4
#define DK_ 256
#define BL_ 8192
#define C_ 1024
#define NCH_ 128
#define GQP_c 128
#define NS_c 6
#define GIN_c 134
#define GH_c 134

typedef __attribute__((ext_vector_type(8))) short short8;
typedef __attribute__((ext_vector_type(4))) float f32x4;

// ---------------- helpers ----------------
__device__ __forceinline__ float block_sum256(float v, float* red) {
  int t = threadIdx.x;
  #pragma unroll
  for (int o = 32; o > 0; o >>= 1) v += __shfl_down(v, o, 64);
  __syncthreads();
  if ((t & 63) == 0) red[t >> 6] = v;
  __syncthreads();
  return red[0] + red[1] + red[2] + red[3];
}

__device__ __forceinline__ unsigned short bf16bits(float f) {
  __hip_bfloat16 h = __float2bfloat16(f);
  return *(unsigned short*)&h;
}

__device__ __forceinline__ float bits2f(unsigned short u) {
  unsigned int x = ((unsigned int)u) << 16;
  return *(float*)&x;
}

__device__ __forceinline__ float4 fma4(float4 a, float4 b, float4 c) {
  return make_float4(fmaf(a.x, b.x, c.x), fmaf(a.y, b.y, c.y),
                     fmaf(a.z, b.z, c.z), fmaf(a.w, b.w, c.w));
}

__device__ __forceinline__ void gload_lds16(const void* g, void* l) {
  __builtin_amdgcn_global_load_lds(
      (const __attribute__((address_space(1))) void*)g,
      (__attribute__((address_space(3))) void*)l, 16, 0, 0);
}

// ---------------- f32 -> bf16 convert ----------------
__global__ __launch_bounds__(256) void f32_to_bf16_k(const float* __restrict__ in,
    __hip_bfloat16* __restrict__ out) {
  size_t i = ((size_t)blockIdx.x * 256 + threadIdx.x) << 2;
  float4 v = *(const float4*)(in + i);
  ushort4 o;
  o.x = bf16bits(v.x); o.y = bf16bits(v.y); o.z = bf16bits(v.z); o.w = bf16bits(v.w);
  *(ushort4*)((unsigned short*)out + i) = o;
}

// ---------------- transpose W(K,N) f32 -> WT(N,K) bf16 ----------------
__global__ __launch_bounds__(256) void transpose_bf16(const float* __restrict__ W,
    __hip_bfloat16* __restrict__ WT, int K, int N) {
  __shared__ float tile[32][33];
  int t = threadIdx.x;
  int r = t >> 3, c4 = (t & 7) << 2;
  int n0 = blockIdx.x << 5, k0 = blockIdx.y << 5;
  float4 v = *(const float4*)(W + (size_t)(k0 + r) * N + n0 + c4);
  tile[r][c4] = v.x; tile[r][c4 + 1] = v.y; tile[r][c4 + 2] = v.z; tile[r][c4 + 3] = v.w;
  __syncthreads();
  ushort4 o;
  o.x = bf16bits(tile[c4][r]);
  o.y = bf16bits(tile[c4 + 1][r]);
  o.z = bf16bits(tile[c4 + 2][r]);
  o.w = bf16bits(tile[c4 + 3][r]);
  *(ushort4*)((unsigned short*)WT + (size_t)(n0 + r) * K + k0 + c4) = o;
}

// ---------------- small f32 transpose with zero-pad: out[c*OS+r] = in[r*Cc+c] ----------------
__global__ __launch_bounds__(256) void small_transpose(const float* __restrict__ in,
    float* __restrict__ out, int R, int Cc, int OS) {
  int total = Cc * OS;
  for (int e = blockIdx.x * 256 + threadIdx.x; e < total; e += gridDim.x * 256) {
    int cIdx = e / OS, r = e - cIdx * OS;
    out[e] = (r < R) ? in[(size_t)r * Cc + cIdx] : 0.f;
  }
}

// ---------------- Wf1 qg-part -> bf16 BT layout [256 rows][K=128] ----------------
__global__ __launch_bounds__(256) void wf1q_prep(const float* __restrict__ Wf1,
    __hip_bfloat16* __restrict__ out) {
  int idx = blockIdx.x * 256 + threadIdx.x;   // 256*128 = 32768 total
  int u = idx >> 7, i = idx & 127;
  float val = (u < GH_c) ? Wf1[i * GH_c + u] : 0.f;
  out[idx] = __float2bfloat16(val);
}

// ---------------- conv weight transpose: cw[1024][4] -> cwT[4][1024] ----------------
__global__ __launch_bounds__(256) void conv_prep(const float* __restrict__ cw,
    float* __restrict__ cwT) {
  int t = blockIdx.x * 256 + threadIdx.x;   // 4096 total
  int j = t >> 10, c = t & (C_ - 1);
  cwT[t] = cw[(c << 2) + j];
}

// ---------------- bf16 MFMA GEMM (m97 structure) ----------------
__global__ __launch_bounds__(256) void gemm_bf16(
    const __hip_bfloat16* __restrict__ A, const __hip_bfloat16* __restrict__ BT,
    const float* __restrict__ bias, float* __restrict__ C, int M, int N, int K) {
  __shared__ __align__(16) __hip_bfloat16 Asm[4096];
  __shared__ __align__(16) __hip_bfloat16 Bsm[4096];
  int tid = threadIdx.x;
  int lane = tid & 63, wave = tid >> 6;
  int wm = wave >> 1, wn = wave & 1;
  int rowBase = blockIdx.y * 128, colBase = blockIdx.x * 128;
  f32x4 acc[4][4];
  #pragma unroll
  for (int i = 0; i < 4; ++i)
    #pragma unroll
    for (int j = 0; j < 4; ++j) acc[i][j] = (f32x4){0.f, 0.f, 0.f, 0.f};

  for (int kt = 0; kt < K; kt += 32) {
    __syncthreads();
    #pragma unroll
    for (int it = 0; it < 2; ++it) {
      int s = tid + (it << 8);
      int T = s >> 6, q = (s >> 4) & 3, m = s & 15;
      const __hip_bfloat16* ga = A + (size_t)(rowBase + T * 16 + m) * K + kt + q * 8;
      gload_lds16(ga, Asm + s * 8);
      const __hip_bfloat16* gb = BT + (size_t)(colBase + T * 16 + m) * K + kt + q * 8;
      gload_lds16(gb, Bsm + s * 8);
    }
    __syncthreads();
    short8 af[4], bfr[4];
    #pragma unroll
    for (int i = 0; i < 4; ++i) {
      af[i]  = *(const short8*)(Asm + ((wm * 4 + i) << 9) + lane * 8);
      bfr[i] = *(const short8*)(Bsm + ((wn * 4 + i) << 9) + lane * 8);
    }
    #pragma unroll
    for (int i = 0; i < 4; ++i)
      #pragma unroll
      for (int j = 0; j < 4; ++j)
        acc[i][j] = __builtin_amdgcn_mfma_f32_16x16x32_bf16(af[i], bfr[j], acc[i][j], 0, 0, 0);
  }
  int r0 = (lane >> 4) * 4, c0 = lane & 15;
  #pragma unroll
  for (int i = 0; i < 4; ++i) {
    int row = rowBase + (wm * 4 + i) * 16 + r0;
    #pragma unroll
    for (int j = 0; j < 4; ++j) {
      int col = colBase + (wn * 4 + j) * 16 + c0;
      float bs = bias ? bias[col] : 0.f;
      #pragma unroll
      for (int r = 0; r < 4; ++r)
        C[(size_t)(row + r) * N + col] = acc[i][j][r] + bs;
    }
  }
}

// ---------------- depthwise causal conv (K=4) + SiLU, float4 over channels ----------------
// Bit-identical per element to the scalar version (same j-order fma chain per
// channel); channels are independent outputs. Weights pre-transposed [4][1024].
__global__ __launch_bounds__(256) void conv_silu_v4(const float* __restrict__ in,
    const float* __restrict__ wT, float* __restrict__ out) {
  int f = blockIdx.x * 256 + threadIdx.x;   // float4 index
  int e = f << 2;
  int c = e & (C_ - 1);
  int l = (e >> 10) & (L_ - 1);
  float4 acc = make_float4(0.f, 0.f, 0.f, 0.f);
  #pragma unroll
  for (int j = 0; j < 4; ++j) {
    int ll = l - 3 + j;
    if (ll >= 0) {
      float4 vj = *(const float4*)(in + e + ((j - 3) << 10));
      float4 wj = *(const float4*)(wT + (j << 10) + c);
      acc = fma4(wj, vj, acc);
    }
  }
  float4 o;
  o.x = acc.x / (1.f + expf(-acc.x));
  o.y = acc.y / (1.f + expf(-acc.y));
  o.z = acc.z / (1.f + expf(-acc.z));
  o.w = acc.w / (1.f + expf(-acc.w));
  *(float4*)(out + e) = o;
}

// ---------------- beta = sigmoid(x @ Wb) ----------------
__global__ __launch_bounds__(256) void beta_kernel(const float* __restrict__ x,
    const float* __restrict__ Wb, float* __restrict__ beta) {
  int row = blockIdx.x;
  int t = threadIdx.x;
  int h = t >> 6, lane = t & 63;
  const float* xr = x + (size_t)row * D_;
  float acc = 0.f;
  for (int k = lane; k < D_; k += 64) acc += xr[k] * Wb[(k << 2) + h];
  #pragma unroll
  for (int o = 32; o > 0; o >>= 1) acc += __shfl_down(acc, o, 64);
  if (lane == 0) beta[(row << 2) + h] = 1.f / (1.f + expf(-acc));
}

// ---------------- l2norm q,k; v*beta; kb; transpose BLHD -> BHLD ----------------
__global__ __launch_bounds__(256) void precompute(const float* __restrict__ q,
    const float* __restrict__ k, const float* __restrict__ v,
    const float* __restrict__ beta,
    float* __restrict__ qn, float* __restrict__ kn,
    float* __restrict__ vb, float* __restrict__ kb) {
  __shared__ float red[4];
  int bid = blockIdx.x;
  int t = threadIdx.x;
  int b = bid >> 14;
  int h = (bid >> 12) & 3;
  int l = bid & (L_ - 1);
  size_t in_off = (((size_t)(b * L_ + l)) << 10) + (h << 8) + t;
  float qv = q[in_off], kv = k[in_off], vv = v[in_off];
  float sq = block_sum256(qv * qv, red);
  float sk = block_sum256(kv * kv, red);
  float rq = rsqrtf(sq + 1e-6f);
  float rk = rsqrtf(sk + 1e-6f);
  float bt = beta[((b * L_ + l) << 2) + h];
  size_t oo = ((size_t)bid << 8) + t;
  float knv = kv * rk;
  qn[oo] = qv * rq;
  kn[oo] = knv;
  vb[oo] = vv * bt;
  kb[oo] = knv * bt;
}

// ---------------- per-chunk: inv (fwd-subst, bf16-rounded) + attn + knT + qn_bf ----------------
__global__ __launch_bounds__(256) void inv_attn(const float* __restrict__ qn,
    const float* kn, const float* __restrict__ kb,
    float* __restrict__ invb, __hip_bfloat16* __restrict__ att_bf,
    __hip_bfloat16* knT_bf) {
  __shared__ float kn_s[32][257];
  __shared__ float inv_s[32][33];
  int ci = blockIdx.x;
  int t = threadIdx.x;
  size_t base = ((size_t)ci) << 13;
  for (int e = t; e < 8192; e += 256) kn_s[e >> 8][e & 255] = kn[base + e];
  __syncthreads();
  {
    unsigned short tmp[32];
    #pragma unroll
    for (int j = 0; j < 32; ++j) tmp[j] = bf16bits(kn_s[j][t]);
    unsigned short* kd = (unsigned short*)knT_bf + (((size_t)ci) << 14) +
                         (size_t)(t >> 4) * 512 + (size_t)(t & 15) * 8;
    #pragma unroll
    for (int g = 0; g < 4; ++g) *(uint4*)(kd + g * 128) = ((const uint4*)tmp)[g];
  }
  {
    int r = t >> 3, kt = t & 7;
    const float4* qrow = (const float4*)(qn + base + (size_t)r * 256 + (kt << 5));
    unsigned short tmp[32];
    #pragma unroll
    for (int i = 0; i < 8; ++i) {
      float4 f = qrow[i];
      tmp[i * 4 + 0] = bf16bits(f.x); tmp[i * 4 + 1] = bf16bits(f.y);
      tmp[i * 4 + 2] = bf16bits(f.z); tmp[i * 4 + 3] = bf16bits(f.w);
    }
    unsigned short* qd = (unsigned short*)knT_bf + (((size_t)ci) << 14) + 8192 +
                         (size_t)(((r >> 4) << 3) + kt) * 512 + (size_t)(r & 15) * 8;
    #pragma unroll
    for (int g = 0; g < 4; ++g) *(uint4*)(qd + g * 128) = ((const uint4*)tmp)[g];
  }
  #pragma unroll
  for (int p = 0; p < 4; ++p) {
    int e = t + (p << 8);
    int i = e >> 5, j = e & 31;
    const float* kbi = kb + base + (i << 8);
    const float* qni = qn + base + (i << 8);
    float am = 0.f, aa = 0.f;
    for (int kk = 0; kk < 256; ++kk) {
      float knv = kn_s[j][kk];
      am += kbi[kk] * knv;
      aa += qni[kk] * knv;
    }
    inv_s[i][j] = (j < i) ? -am : 0.f;
    ((unsigned short*)att_bf)[((size_t)ci << 10) + (size_t)(i >> 4) * 512 +
        (size_t)((i & 15) + ((j >> 3) << 4)) * 8 + (j & 7)] =
        bf16bits((j <= i) ? aa : 0.f);
  }
  __syncthreads();
  for (int i = 1; i < 32; ++i) {
    float upd = 0.f;
    if (t < i) {
      for (int kk = t + 1; kk < i; ++kk) upd += inv_s[i][kk] * inv_s[kk][t];
    }
    __syncthreads();
    if (t < i) inv_s[i][t] += upd;
    __syncthreads();
  }
  #pragma unroll
  for (int p = 0; p < 4; ++p) {
    int e = t + (p << 8);
    int i = e >> 5, j = e & 31;
    float val = inv_s[i][j] + (i == j ? 1.f : 0.f);
    val = __bfloat162float(__float2bfloat16(val));
    invb[((size_t)ci << 10) + e] = val;
  }
}

// ---------------- u = inv@vb (in place f32); w = -(inv@kb) as bf16 frag-order ----------------
__global__ __launch_bounds__(256) void uw_kernel(const float* __restrict__ invb,
    float* __restrict__ vb_u, float* kb_w, __hip_bfloat16* w_bf) {
  __shared__ float inv_s[32][33];
  __shared__ float tile[32][260];
  int ci = blockIdx.x, t = threadIdx.x;
  size_t base = ((size_t)ci) << 13;
  for (int e = t; e < 1024; e += 256) inv_s[e >> 5][e & 31] = invb[((size_t)ci << 10) + e];
  for (int ph = 0; ph < 2; ++ph) {
    const float* src = (ph == 0) ? vb_u : kb_w;
    __syncthreads();
    for (int f = t; f < 2048; f += 256) {
      int e = f << 2;
      *(float4*)&tile[e >> 8][e & 255] = *(const float4*)(src + base + e);
    }
    __syncthreads();
    int c4 = (t & 63) << 2;
    int ig = t >> 6;
    float4 acc[8];
    #pragma unroll
    for (int ii = 0; ii < 8; ++ii) acc[ii] = make_float4(0.f, 0.f, 0.f, 0.f);
    for (int j = 0; j < 32; ++j) {
      float4 v4 = *(const float4*)&tile[j][c4];
      #pragma unroll
      for (int ii = 0; ii < 8; ++ii) {
        float iv = inv_s[(ig << 3) + ii][j];
        acc[ii].x += iv * v4.x; acc[ii].y += iv * v4.y;
        acc[ii].z += iv * v4.z; acc[ii].w += iv * v4.w;
      }
    }
    #pragma unroll
    for (int ii = 0; ii < 8; ++ii) {
      int i = (ig << 3) + ii;
      if (ph == 0) {
        *(float4*)(vb_u + base + (i << 8) + c4) = acc[ii];
      } else {
        ushort4 o;
        o.x = bf16bits(-acc[ii].x); o.y = bf16bits(-acc[ii].y);
        o.z = bf16bits(-acc[ii].z); o.w = bf16bits(-acc[ii].w);
        unsigned short* wd = (unsigned short*)w_bf + (((size_t)ci) << 14) +
            (size_t)(((i >> 4) << 3) + (c4 >> 5)) * 512 +
            (size_t)((i & 15) + (((c4 >> 3) & 3) << 4)) * 8 + (c4 & 7);
        *(ushort4*)wd = o;
      }
    }
  }
}

// ---------------- single-wave MFMA scan, register-direct operands (round-4 best) ----------------
__global__ __launch_bounds__(64, 1) void scan_kernel(
    const __hip_bfloat16* __restrict__ w_bf,
    const __hip_bfloat16* __restrict__ kq_bf,
    const __hip_bfloat16* __restrict__ att_bf,
    const float* __restrict__ u, float* __restrict__ dout) {
  __shared__ __align__(16) unsigned short Sim[2][2][16 * 264];
  __shared__ __align__(16) float UtT[16 * 36];
  int lane = threadIdx.x;
  int mlane = lane & 15, quad = lane >> 4;
  int bh = blockIdx.x & 7;
  int cb = blockIdx.x >> 3;
  int cbase = cb << 4;

  const unsigned short* wbase = (const unsigned short*)w_bf;
  const unsigned short* kqbase = (const unsigned short*)kq_bf;
  const unsigned short* abase = (const unsigned short*)att_bf;

  short8 Wr[16], Qr[16], Kr[16], Ar[2];
  float ur[8], urn[8];

  auto load_WQ = [&](int nc) {
    size_t cb14 = ((size_t)(bh * NCH_ + nc)) << 14;
    const short8* wg = (const short8*)(wbase + cb14 + (size_t)lane * 8);
    const short8* qg = (const short8*)(kqbase + cb14 + 8192 + (size_t)lane * 8);
    #pragma unroll
    for (int s = 0; s < 16; ++s) { Wr[s] = wg[s * 64]; Qr[s] = qg[s * 64]; }
  };
  auto load_K = [&](int nc) {
    size_t cb14 = ((size_t)(bh * NCH_ + nc)) << 14;
    const short8* kg = (const short8*)(kqbase + cb14 + (size_t)lane * 8);
    #pragma unroll
    for (int s = 0; s < 16; ++s) Kr[s] = kg[s * 64];
  };
  auto load_A = [&](int nc) {
    const short8* ag = (const short8*)(abase + (((size_t)(bh * NCH_ + nc)) << 10) +
                                       (size_t)lane * 8);
    Ar[0] = ag[0]; Ar[1] = ag[64];
  };
  auto load_u8 = [&](int nc, float* dst) {
    size_t cbf = ((size_t)(bh * NCH_ + nc)) << 13;
    const float* up = u + cbf + (size_t)(quad * 4) * 256 + cbase + mlane;
    #pragma unroll
    for (int tt = 0; tt < 2; ++tt)
      #pragma unroll
      for (int r = 0; r < 4; ++r) dst[tt * 4 + r] = up[(tt * 16 + r) * 256];
  };

  for (int e = lane; e < 16 * 264; e += 64) { Sim[0][0][e] = 0; Sim[0][1][e] = 0; }
  f32x4 accS[16];
  #pragma unroll
  for (int i = 0; i < 16; ++i) accS[i] = (f32x4){0.f, 0.f, 0.f, 0.f};

  load_WQ(0);
  load_K(0);
  load_A(0);
  load_u8(0, ur);

  for (int nc = 0; nc < NCH_; ++nc) {
    int cur = nc & 1, alt = cur ^ 1;
    int nn = nc + 1 < NCH_ ? nc + 1 : NCH_ - 1;

    f32x4 uh0 = (f32x4){ur[0], ur[1], ur[2], ur[3]};
    f32x4 uh1 = (f32x4){ur[4], ur[5], ur[6], ur[7]};
    f32x4 ul0 = (f32x4){0.f, 0.f, 0.f, 0.f}, ul1 = (f32x4){0.f, 0.f, 0.f, 0.f};
    f32x4 oh0 = (f32x4){0.f, 0.f, 0.f, 0.f}, oh1 = (f32x4){0.f, 0.f, 0.f, 0.f};
    f32x4 ol0 = (f32x4){0.f, 0.f, 0.f, 0.f}, ol1 = (f32x4){0.f, 0.f, 0.f, 0.f};
    #pragma unroll
    for (int kt = 0; kt < 8; ++kt) {
      short8 bhi = *(const short8*)&Sim[cur][0][mlane * 264 + kt * 32 + quad * 8];
      short8 blo = *(const short8*)&Sim[cur][1][mlane * 264 + kt * 32 + quad * 8];
      uh0 = __builtin_amdgcn_mfma_f32_16x16x32_bf16(Wr[kt], bhi, uh0, 0, 0, 0);
      ul0 = __builtin_amdgcn_mfma_f32_16x16x32_bf16(Wr[kt], blo, ul0, 0, 0, 0);
      uh1 = __builtin_amdgcn_mfma_f32_16x16x32_bf16(Wr[8 + kt], bhi, uh1, 0, 0, 0);
      ul1 = __builtin_amdgcn_mfma_f32_16x16x32_bf16(Wr[8 + kt], blo, ul1, 0, 0, 0);
      oh0 = __builtin_amdgcn_mfma_f32_16x16x32_bf16(Qr[kt], bhi, oh0, 0, 0, 0);
      ol0 = __builtin_amdgcn_mfma_f32_16x16x32_bf16(Qr[kt], blo, ol0, 0, 0, 0);
      oh1 = __builtin_amdgcn_mfma_f32_16x16x32_bf16(Qr[8 + kt], bhi, oh1, 0, 0, 0);
      ol1 = __builtin_amdgcn_mfma_f32_16x16x32_bf16(Qr[8 + kt], blo, ol1, 0, 0, 0);
    }
    f32x4 ut0 = uh0 + ul0, ut1 = uh1 + ul1;
    *(f32x4*)&UtT[mlane * 36 + quad * 4] = ut0;
    *(f32x4*)&UtT[mlane * 36 + 16 + quad * 4] = ut1;
    load_WQ(nn);
    load_u8(nn, urn);
    short8 but;
    {
      const float* up = &UtT[mlane * 36 + quad * 8];
      #pragma unroll
      for (int j = 0; j < 8; ++j) but[j] = (short)bf16bits(up[j]);
    }
    f32x4 o0 = oh0 + ol0, o1 = oh1 + ol1;
    o0 = __builtin_amdgcn_mfma_f32_16x16x32_bf16(Ar[0], but, o0, 0, 0, 0);
    o1 = __builtin_amdgcn_mfma_f32_16x16x32_bf16(Ar[1], but, o1, 0, 0, 0);
    load_A(nn);
    size_t cbf = ((size_t)(bh * NCH_ + nc)) << 13;
    float* op = dout + cbf + (size_t)(quad * 4) * 256 + cbase + mlane;
    #pragma unroll
    for (int r = 0; r < 4; ++r) { op[r * 256] = o0[r]; op[(16 + r) * 256] = o1[r]; }
    #pragma unroll
    for (int t2 = 0; t2 < 16; ++t2) {
      accS[t2] = __builtin_amdgcn_mfma_f32_16x16x32_bf16(Kr[t2], but, accS[t2], 0, 0, 0);
      unsigned short nh[4], nl[4];
      #pragma unroll
      for (int r = 0; r < 4; ++r) {
        float sv = accS[t2][r];
        unsigned short hb = bf16bits(sv);
        nh[r] = hb;
        nl[r] = bf16bits(sv - bits2f(hb));
      }
      *(uint2*)&Sim[alt][0][mlane * 264 + t2 * 16 + quad * 4] = *(const uint2*)nh;
      *(uint2*)&Sim[alt][1][mlane * 264 + t2 * 16 + quad * 4] = *(const uint2*)nl;
    }
    load_K(nn);
    #pragma unroll
    for (int r = 0; r < 8; ++r) ur[r] = urn[r];
  }
}

// ---------------- gate: NL=8 tokens/block; shared qg-matvec hoisted to qgH GEMM ----------------
__global__ __launch_bounds__(256, 1) void gate_kernel(
    const float* __restrict__ v, const float* __restrict__ delta,
    const float* __restrict__ qgH,
    const float* __restrict__ fw0, const float* __restrict__ fw1T,
    const float* __restrict__ fw2T, const float* __restrict__ fw3T,
    const float* __restrict__ Wf1, const float* __restrict__ Wf2,
    const float* __restrict__ bf1, const float* __restrict__ bf2,
    const float* __restrict__ ltm, const float* __restrict__ onw,
    __hip_bfloat16* __restrict__ obf) {
  __shared__ float W1t[6][136];   // Wf1 rows 128..133 (summary tail)
  __shared__ float W2f[804];      // Wf2 [134][6] flat
  __shared__ float bf1s[136];
  int t = threadIdx.x;
  int wave = t >> 6, lane = t & 63;
  for (int e = t; e < 804; e += 256) {
    int s = e / 134, u = e - s * 134;
    W1t[s][u] = Wf1[(128 + s) * GH_c + u];
    W2f[e] = Wf2[e];
  }
  if (t < GH_c) bf1s[t] = bf1[t];
  __syncthreads();

  int bid = blockIdx.x;
  int bl0 = (((bid & 7) << 7) | (bid >> 3)) << 3;   // 1024 blocks -> 8 tokens each
  int b = bl0 >> 12;
  int h = wave;
  int c = (h << 8) + (lane << 2);

  float4 fw3r[15], fw2r[7], fw1r[3], fw0r;
  #pragma unroll
  for (int j = 0; j < 15; ++j) fw3r[j] = *(const float4*)(fw3T + (j << 10) + c);
  #pragma unroll
  for (int j = 0; j < 7; ++j) fw2r[j] = *(const float4*)(fw2T + (j << 10) + c);
  #pragma unroll
  for (int j = 0; j < 3; ++j) fw1r[j] = *(const float4*)(fw1T + (j << 10) + c);
  fw0r = *(const float4*)(fw0 + c);
  float4 ow = *(const float4*)(onw + (lane << 2));
  float itemp = expf(ltm[h]);
  float b2r[6];
  #pragma unroll
  for (int s = 0; s < 6; ++s) b2r[s] = bf2[s];
  int u3 = 128 + (lane < 6 ? lane : 0);

  auto gelu = [](float a) -> float {
    return 0.5f * a * (1.f + erff(a * 0.70710678f));
  };

  for (int tk = 0; tk < 8; ++tk) {
    int bl = bl0 + tk;
    int l = bl & (L_ - 1);
    float4 st0, st1, st2, st3, st4, st5;
    st1 = make_float4(0, 0, 0, 0);
    st2 = make_float4(0, 0, 0, 0);
    st3 = make_float4(0, 0, 0, 0);
    #pragma unroll
    for (int j = 0; j < 15; ++j) {
      int ll = l - 14 + j;
      float4 vj = make_float4(0, 0, 0, 0);
      if (ll >= 0) vj = *(const float4*)(v + ((((size_t)(b * L_ + ll)) << 10) + c));
      st3 = fma4(fw3r[j], vj, st3);
      if (j >= 8) st2 = fma4(fw2r[j - 8], vj, st2);
      if (j >= 12) st1 = fma4(fw1r[j - 12], vj, st1);
      if (j == 14) {
        st0 = make_float4(fw0r.x * vj.x, fw0r.y * vj.y, fw0r.z * vj.z, fw0r.w * vj.w);
        st5 = vj;
      }
    }
    st4 = *(const float4*)(delta + ((((size_t)((b * H_ + h) * L_ + l)) << 8) + (lane << 2)));

    float s0 = st0.x + st0.y + st0.z + st0.w;
    float s1 = st1.x + st1.y + st1.z + st1.w;
    float s2 = st2.x + st2.y + st2.z + st2.w;
    float s3 = st3.x + st3.y + st3.z + st3.w;
    float s4 = st4.x + st4.y + st4.z + st4.w;
    float s5 = st5.x + st5.y + st5.z + st5.w;
    #pragma unroll
    for (int o = 32; o > 0; o >>= 1) {
      s0 += __shfl_down(s0, o, 64); s1 += __shfl_down(s1, o, 64);
      s2 += __shfl_down(s2, o, 64); s3 += __shfl_down(s3, o, 64);
      s4 += __shfl_down(s4, o, 64); s5 += __shfl_down(s5, o, 64);
    }
    float ss_[6];
    ss_[0] = __shfl(s0, 0, 64) * (1.f / 256.f);
    ss_[1] = __shfl(s1, 0, 64) * (1.f / 256.f);
    ss_[2] = __shfl(s2, 0, 64) * (1.f / 256.f);
    ss_[3] = __shfl(s3, 0, 64) * (1.f / 256.f);
    ss_[4] = __shfl(s4, 0, 64) * (1.f / 256.f);
    ss_[5] = __shfl(s5, 0, 64) * (1.f / 256.f);

    const float* qr = qgH + ((size_t)bl << 8);
    float a0 = qr[lane] + bf1s[lane];
    float a1 = qr[64 + lane] + bf1s[64 + lane];
    float a2 = qr[u3] + bf1s[u3];
    #pragma unroll
    for (int s = 0; s < 6; ++s) {
      a0 = fmaf(W1t[s][lane], ss_[s], a0);
      a1 = fmaf(W1t[s][64 + lane], ss_[s], a1);
      a2 = fmaf(W1t[s][u3], ss_[s], a2);
    }
    float h0 = gelu(a0);
    float h1 = gelu(a1);
    float h2 = (lane < 6) ? gelu(a2) : 0.f;

    const float* w2a = W2f + lane * 6;
    const float* w2b = W2f + (64 + lane) * 6;
    const float* w2c = W2f + u3 * 6;
    float t0 = h0 * w2a[0] + h1 * w2b[0] + h2 * w2c[0];
    float t1 = h0 * w2a[1] + h1 * w2b[1] + h2 * w2c[1];
    float t2 = h0 * w2a[2] + h1 * w2b[2] + h2 * w2c[2];
    float t3 = h0 * w2a[3] + h1 * w2b[3] + h2 * w2c[3];
    float t4 = h0 * w2a[4] + h1 * w2b[4] + h2 * w2c[4];
    float t5 = h0 * w2a[5] + h1 * w2b[5] + h2 * w2c[5];
    #pragma unroll
    for (int o = 32; o > 0; o >>= 1) {
      t0 += __shfl_down(t0, o, 64); t1 += __shfl_down(t1, o, 64);
      t2 += __shfl_down(t2, o, 64); t3 += __shfl_down(t3, o, 64);
      t4 += __shfl_down(t4, o, 64); t5 += __shfl_down(t5, o, 64);
    }
    float p0, p1, p2, p3, p4, p5;
    if (lane == 0) {
      float l0v = (t0 + b2r[0]) / itemp, l1v = (t1 + b2r[1]) / itemp;
      float l2v = (t2 + b2r[2]) / itemp, l3v = (t3 + b2r[3]) / itemp;
      float l4v = (t4 + b2r[4]) / itemp, l5v = (t5 + b2r[5]) / itemp;
      float m = fmaxf(fmaxf(fmaxf(l0v, l1v), fmaxf(l2v, l3v)), fmaxf(l4v, l5v));
      float e0 = expf(l0v - m), e1 = expf(l1v - m), e2 = expf(l2v - m);
      float e3 = expf(l3v - m), e4 = expf(l4v - m), e5 = expf(l5v - m);
      float inv = 1.f / (e0 + e1 + e2 + e3 + e4 + e5);
      p0 = e0 * inv * 0.88f + 0.02f; p1 = e1 * inv * 0.88f + 0.02f;
      p2 = e2 * inv * 0.88f + 0.02f; p3 = e3 * inv * 0.88f + 0.02f;
      p4 = e4 * inv * 0.88f + 0.02f; p5 = e5 * inv * 0.88f + 0.02f;
    }
    p0 = __shfl(p0, 0, 64); p1 = __shfl(p1, 0, 64); p2 = __shfl(p2, 0, 64);
    p3 = __shfl(p3, 0, 64); p4 = __shfl(p4, 0, 64); p5 = __shfl(p5, 0, 64);

    float4 fu;
    fu.x = p0 * st0.x + p1 * st1.x + p2 * st2.x + p3 * st3.x + p4 * st4.x + p5 * st5.x;
    fu.y = p0 * st0.y + p1 * st1.y + p2 * st2.y + p3 * st3.y + p4 * st4.y + p5 * st5.y;
    fu.z = p0 * st0.z + p1 * st1.z + p2 * st2.z + p3 * st3.z + p4 * st4.z + p5 * st5.z;
    fu.w = p0 * st0.w + p1 * st1.w + p2 * st2.w + p3 * st3.w + p4 * st4.w + p5 * st5.w;
    float ssq = fu.x * fu.x + fu.y * fu.y + fu.z * fu.z + fu.w * fu.w;
    #pragma unroll
    for (int o = 32; o > 0; o >>= 1) ssq += __shfl_xor(ssq, o, 64);
    float sc = rsqrtf(ssq * (1.f / 256.f) + 1e-5f);
    ushort4 ob;
    ob.x = bf16bits(fu.x * sc * ow.x);
    ob.y = bf16bits(fu.y * sc * ow.y);
    ob.z = bf16bits(fu.z * sc * ow.z);
    ob.w = bf16bits(fu.w * sc * ow.w);
    *(ushort4*)((unsigned short*)obf + (((size_t)bl) << 10) + c) = ob;
  }
}

// ---------------- launch ----------------
extern "C" void kernel_launch(void* const* d_in, const int* in_sizes, int n_in,
                              void* d_out, int out_size, void* d_ws, size_t ws_size,
                              hipStream_t stream) {
  const float* x   = (const float*)d_in[0];
  const float* Wq  = (const float*)d_in[1];
  const float* Wk  = (const float*)d_in[2];
  const float* Wv  = (const float*)d_in[3];
  const float* Wb  = (const float*)d_in[4];
  const float* cqw = (const float*)d_in[5];
  const float* ckw = (const float*)d_in[6];
  const float* cvw = (const float*)d_in[7];
  const float* fw0 = (const float*)d_in[8];
  const float* fw1 = (const float*)d_in[9];
  const float* fw2 = (const float*)d_in[10];
  const float* fw3 = (const float*)d_in[11];
  const float* Wqg = (const float*)d_in[12];
  const float* bqg = (const float*)d_in[13];
  const float* Wf1 = (const float*)d_in[14];
  const float* bf1 = (const float*)d_in[15];
  const float* Wf2 = (const float*)d_in[16];
  const float* bf2 = (const float*)d_in[17];
  const float* ltm = (const float*)d_in[18];
  const float* onw = (const float*)d_in[19];
  const float* Wo  = (const float*)d_in[20];
  float* out = (float*)d_out;
  float* ws = (float*)d_ws;

  const size_t BIG = (size_t)BL_ * C_;
  float* qpre = ws;                 // -> qn f32 -> gate_bf after scan
  float* kpre = ws + BIG;           // -> kn f32 -> knT_bf+qn_bf (frag-order, in-place)
  float* vpre = ws + 2 * BIG;       // -> vb -> u f32
  float* qs   = ws + 3 * BIG;       // x_bf early -> conv q -> delta_out
  float* ks   = ws + 4 * BIG;       // conv k (scratch) -> qgH/qg_bf/wf1qT after precompute
  float* vs   = ws + 5 * BIG;       // conv v (FIR/v_direct)
  float* kbw  = ws + 6 * BIG;       // wT bf16 early -> kb -> w_bf (frag-order) -> woT
  float* invb = ws + 7 * BIG;
  float* attb = invb + (size_t)1024 * 1024;
  float* beta = attb + (size_t)1024 * 1024;
  float* qg   = beta + (size_t)BL_ * H_;

  __hip_bfloat16* x_bf  = (__hip_bfloat16*)qs;
  __hip_bfloat16* wqT   = (__hip_bfloat16*)kbw;
  __hip_bfloat16* wkT   = wqT + (size_t)1024 * 1024;
  __hip_bfloat16* wvT   = wkT + (size_t)1024 * 1024;
  __hip_bfloat16* wqgT  = wvT + (size_t)1024 * 1024;
  __hip_bfloat16* woT   = (__hip_bfloat16*)kbw;
  __hip_bfloat16* gate_bf = (__hip_bfloat16*)qpre;
  __hip_bfloat16* knT_bf = (__hip_bfloat16*)kpre;   // + qn_bf in slot second halves
  __hip_bfloat16* w_bf   = (__hip_bfloat16*)kbw;
  __hip_bfloat16* att_bf = (__hip_bfloat16*)attb;
  float* scr   = attb + (size_t)600000;
  float* fw1T  = scr;
  float* fw2T  = scr + 3072;
  float* fw3T  = scr + 10240;
  float* cqwT  = scr + 25600;       // [4][1024] transposed conv weights
  float* ckwT  = scr + 29696;
  float* cvwT  = scr + 33792;

  float* qgH = ks;                                            // 8192 x 256 f32
  __hip_bfloat16* qg_bf  = (__hip_bfloat16*)(ks + (size_t)3 * 1024 * 1024);
  __hip_bfloat16* wf1qT  = (__hip_bfloat16*)(ks + (size_t)4 * 1024 * 1024);

  dim3 blk(256);
  f32_to_bf16_k<<<dim3(BL_ * D_ / 1024), blk, 0, stream>>>(x, x_bf);
  transpose_bf16<<<dim3(32, 32), blk, 0, stream>>>(Wq, wqT, D_, C_);
  transpose_bf16<<<dim3(32, 32), blk, 0, stream>>>(Wk, wkT, D_, C_);
  transpose_bf16<<<dim3(32, 32), blk, 0, stream>>>(Wv, wvT, D_, C_);
  transpose_bf16<<<dim3(4, 32), blk, 0, stream>>>(Wqg, wqgT, D_, GQP_c);
  small_transpose<<<dim3(16), blk, 0, stream>>>(fw1, fw1T, 1024, 3, 1024);
  small_transpose<<<dim3(32), blk, 0, stream>>>(fw2, fw2T, 1024, 7, 1024);
  small_transpose<<<dim3(64), blk, 0, stream>>>(fw3, fw3T, 1024, 15, 1024);
  conv_prep<<<dim3(16), blk, 0, stream>>>(cqw, cqwT);
  conv_prep<<<dim3(16), blk, 0, stream>>>(ckw, ckwT);
  conv_prep<<<dim3(16), blk, 0, stream>>>(cvw, cvwT);
  gemm_bf16<<<dim3(8, 64), blk, 0, stream>>>(x_bf, wqT, nullptr, qpre, BL_, C_, D_);
  gemm_bf16<<<dim3(8, 64), blk, 0, stream>>>(x_bf, wkT, nullptr, kpre, BL_, C_, D_);
  gemm_bf16<<<dim3(8, 64), blk, 0, stream>>>(x_bf, wvT, nullptr, vpre, BL_, C_, D_);
  gemm_bf16<<<dim3(1, 64), blk, 0, stream>>>(x_bf, wqgT, bqg, qg, BL_, GQP_c, D_);
  beta_kernel<<<dim3(BL_), blk, 0, stream>>>(x, Wb, beta);
  conv_silu_v4<<<dim3(BL_ * C_ / 1024), blk, 0, stream>>>(qpre, cqwT, qs);
  conv_silu_v4<<<dim3(BL_ * C_ / 1024), blk, 0, stream>>>(kpre, ckwT, ks);
  conv_silu_v4<<<dim3(BL_ * C_ / 1024), blk, 0, stream>>>(vpre, cvwT, vs);
  precompute<<<dim3(B_ * H_ * L_), blk, 0, stream>>>(qs, ks, vs, beta, qpre, kpre,
                                                     vpre, kbw);
  // ks slot now free: build qgH = qg @ Wf1[0:128,:] (bf16 MFMA, f32 accum)
  f32_to_bf16_k<<<dim3(BL_ * GQP_c / 1024), blk, 0, stream>>>(qg, qg_bf);
  wf1q_prep<<<dim3(128), blk, 0, stream>>>(Wf1, wf1qT);
  gemm_bf16<<<dim3(2, 64), blk, 0, stream>>>(qg_bf, wf1qT, nullptr, qgH, BL_, 256, 128);
  inv_attn<<<dim3(1024), blk, 0, stream>>>(qpre, kpre, kbw, invb, att_bf, knT_bf);
  uw_kernel<<<dim3(1024), blk, 0, stream>>>(invb, vpre, kbw, w_bf);
  scan_kernel<<<dim3(128), dim3(64), 0, stream>>>(w_bf, knT_bf, att_bf, vpre, qs);
  transpose_bf16<<<dim3(32, 32), blk, 0, stream>>>(Wo, woT, C_, D_);
  gate_kernel<<<dim3(1024), blk, 0, stream>>>(vs, qs, qgH, fw0, fw1T, fw2T, fw3T,
                                              Wf1, Wf2, bf1, bf2, ltm, onw, gate_bf);
  gemm_bf16<<<dim3(8, 64), blk, 0, stream>>>(gate_bf, woT, nullptr, out, BL_, D_, C_);
}

// Round 10
// 887.955 us; speedup vs baseline: 1.2189x; 1.0629x over previous
//
#include <hip/hip_runtime.h>
#include <hip/hip_bf16.h>
#include <math.h>

#define B_ 2
#define L_ 4096
#define D_ 1024
#define H_ 4
#define DK_ 256
#define BL_ 8192
#define C_ 1024
#define NCH_ 128
#define GQP_c 128
#define NS_c 6
#define GIN_c 134
#define GH_c 134

typedef __attribute__((ext_vector_type(8))) short short8;
typedef __attribute__((ext_vector_type(4))) float f32x4;

// ---------------- helpers ----------------
__device__ __forceinline__ unsigned short bf16bits(float f) {
  __hip_bfloat16 h = __float2bfloat16(f);
  return *(unsigned short*)&h;
}

__device__ __forceinline__ float bits2f(unsigned short u) {
  unsigned int x = ((unsigned int)u) << 16;
  return *(float*)&x;
}

__device__ __forceinline__ float4 fma4(float4 a, float4 b, float4 c) {
  return make_float4(fmaf(a.x, b.x, c.x), fmaf(a.y, b.y, c.y),
                     fmaf(a.z, b.z, c.z), fmaf(a.w, b.w, c.w));
}

__device__ __forceinline__ float4 silu4(float4 a) {
  return make_float4(a.x / (1.f + expf(-a.x)), a.y / (1.f + expf(-a.y)),
                     a.z / (1.f + expf(-a.z)), a.w / (1.f + expf(-a.w)));
}

__device__ __forceinline__ void gload_lds16(const void* g, void* l) {
  __builtin_amdgcn_global_load_lds(
      (const __attribute__((address_space(1))) void*)g,
      (__attribute__((address_space(3))) void*)l, 16, 0, 0);
}

// ---------------- f32 -> bf16 convert ----------------
__global__ __launch_bounds__(256) void f32_to_bf16_k(const float* __restrict__ in,
    __hip_bfloat16* __restrict__ out) {
  size_t i = ((size_t)blockIdx.x * 256 + threadIdx.x) << 2;
  float4 v = *(const float4*)(in + i);
  ushort4 o;
  o.x = bf16bits(v.x); o.y = bf16bits(v.y); o.z = bf16bits(v.z); o.w = bf16bits(v.w);
  *(ushort4*)((unsigned short*)out + i) = o;
}

// ---------------- transpose W(K,N) f32 -> WT(N,K) bf16 ----------------
__global__ __launch_bounds__(256) void transpose_bf16(const float* __restrict__ W,
    __hip_bfloat16* __restrict__ WT, int K, int N) {
  __shared__ float tile[32][33];
  int t = threadIdx.x;
  int r = t >> 3, c4 = (t & 7) << 2;
  int n0 = blockIdx.x << 5, k0 = blockIdx.y << 5;
  float4 v = *(const float4*)(W + (size_t)(k0 + r) * N + n0 + c4);
  tile[r][c4] = v.x; tile[r][c4 + 1] = v.y; tile[r][c4 + 2] = v.z; tile[r][c4 + 3] = v.w;
  __syncthreads();
  ushort4 o;
  o.x = bf16bits(tile[c4][r]);
  o.y = bf16bits(tile[c4 + 1][r]);
  o.z = bf16bits(tile[c4 + 2][r]);
  o.w = bf16bits(tile[c4 + 3][r]);
  *(ushort4*)((unsigned short*)WT + (size_t)(n0 + r) * K + k0 + c4) = o;
}

// ---------------- small f32 transpose with zero-pad: out[c*OS+r] = in[r*Cc+c] ----------------
__global__ __launch_bounds__(256) void small_transpose(const float* __restrict__ in,
    float* __restrict__ out, int R, int Cc, int OS) {
  int total = Cc * OS;
  for (int e = blockIdx.x * 256 + threadIdx.x; e < total; e += gridDim.x * 256) {
    int cIdx = e / OS, r = e - cIdx * OS;
    out[e] = (r < R) ? in[(size_t)r * Cc + cIdx] : 0.f;
  }
}

// ---------------- Wf1 qg-part -> bf16 BT layout [256 rows][K=128] ----------------
__global__ __launch_bounds__(256) void wf1q_prep(const float* __restrict__ Wf1,
    __hip_bfloat16* __restrict__ out) {
  int idx = blockIdx.x * 256 + threadIdx.x;   // 256*128 = 32768 total
  int u = idx >> 7, i = idx & 127;
  float val = (u < GH_c) ? Wf1[i * GH_c + u] : 0.f;
  out[idx] = __float2bfloat16(val);
}

// ---------------- conv weight transpose: cw[1024][4] -> cwT[4][1024] ----------------
__global__ __launch_bounds__(256) void conv_prep(const float* __restrict__ cw,
    float* __restrict__ cwT) {
  int t = blockIdx.x * 256 + threadIdx.x;   // 4096 total
  int j = t >> 10, c = t & (C_ - 1);
  cwT[t] = cw[(c << 2) + j];
}

// ---------------- bf16 MFMA GEMM (m97 structure) ----------------
__global__ __launch_bounds__(256) void gemm_bf16(
    const __hip_bfloat16* __restrict__ A, const __hip_bfloat16* __restrict__ BT,
    const float* __restrict__ bias, float* __restrict__ C, int M, int N, int K) {
  __shared__ __align__(16) __hip_bfloat16 Asm[4096];
  __shared__ __align__(16) __hip_bfloat16 Bsm[4096];
  int tid = threadIdx.x;
  int lane = tid & 63, wave = tid >> 6;
  int wm = wave >> 1, wn = wave & 1;
  int rowBase = blockIdx.y * 128, colBase = blockIdx.x * 128;
  f32x4 acc[4][4];
  #pragma unroll
  for (int i = 0; i < 4; ++i)
    #pragma unroll
    for (int j = 0; j < 4; ++j) acc[i][j] = (f32x4){0.f, 0.f, 0.f, 0.f};

  for (int kt = 0; kt < K; kt += 32) {
    __syncthreads();
    #pragma unroll
    for (int it = 0; it < 2; ++it) {
      int s = tid + (it << 8);
      int T = s >> 6, q = (s >> 4) & 3, m = s & 15;
      const __hip_bfloat16* ga = A + (size_t)(rowBase + T * 16 + m) * K + kt + q * 8;
      gload_lds16(ga, Asm + s * 8);
      const __hip_bfloat16* gb = BT + (size_t)(colBase + T * 16 + m) * K + kt + q * 8;
      gload_lds16(gb, Bsm + s * 8);
    }
    __syncthreads();
    short8 af[4], bfr[4];
    #pragma unroll
    for (int i = 0; i < 4; ++i) {
      af[i]  = *(const short8*)(Asm + ((wm * 4 + i) << 9) + lane * 8);
      bfr[i] = *(const short8*)(Bsm + ((wn * 4 + i) << 9) + lane * 8);
    }
    #pragma unroll
    for (int i = 0; i < 4; ++i)
      #pragma unroll
      for (int j = 0; j < 4; ++j)
        acc[i][j] = __builtin_amdgcn_mfma_f32_16x16x32_bf16(af[i], bfr[j], acc[i][j], 0, 0, 0);
  }
  int r0 = (lane >> 4) * 4, c0 = lane & 15;
  #pragma unroll
  for (int i = 0; i < 4; ++i) {
    int row = rowBase + (wm * 4 + i) * 16 + r0;
    #pragma unroll
    for (int j = 0; j < 4; ++j) {
      int col = colBase + (wn * 4 + j) * 16 + c0;
      float bs = bias ? bias[col] : 0.f;
      #pragma unroll
      for (int r = 0; r < 4; ++r)
        C[(size_t)(row + r) * N + col] = acc[i][j][r] + bs;
    }
  }
}

// ---------------- beta = sigmoid(x @ Wb) ----------------
__global__ __launch_bounds__(256) void beta_kernel(const float* __restrict__ x,
    const float* __restrict__ Wb, float* __restrict__ beta) {
  int row = blockIdx.x;
  int t = threadIdx.x;
  int h = t >> 6, lane = t & 63;
  const float* xr = x + (size_t)row * D_;
  float acc = 0.f;
  for (int k = lane; k < D_; k += 64) acc += xr[k] * Wb[(k << 2) + h];
  #pragma unroll
  for (int o = 32; o > 0; o >>= 1) acc += __shfl_down(acc, o, 64);
  if (lane == 0) beta[(row << 2) + h] = 1.f / (1.f + expf(-acc));
}

// ---------------- fused conv(K=4)+SiLU + l2norm + BLHD->BHLD transpose ----------------
// One block per (b,l); thread t = channels 4t..4t+3; wave = head.
// Replaces 3x conv_silu + precompute. vb/kb are NOT materialized (applied as
// kn*beta / vs*beta at their use sites, bit-identical products). Only numerics
// change vs the old pipeline: the fp32 l2norm summation order (wave butterfly
// over float4 partials instead of block tree) -- ~1e-7 relative, << bf16 ulp.
__global__ __launch_bounds__(256) void conv_norm_fused(
    const float* __restrict__ qpre, const float* __restrict__ kpre,
    const float* __restrict__ vpre,
    const float* __restrict__ cqwT, const float* __restrict__ ckwT,
    const float* __restrict__ cvwT,
    float* __restrict__ vs, float* __restrict__ qn, float* __restrict__ kn) {
  int bid = blockIdx.x;             // b*L + l
  int b = bid >> 12, l = bid & (L_ - 1);
  int t = threadIdx.x;
  int h = t >> 6, lane = t & 63;
  int c = t << 2;
  float4 qa = make_float4(0.f, 0.f, 0.f, 0.f);
  float4 ka = make_float4(0.f, 0.f, 0.f, 0.f);
  float4 va = make_float4(0.f, 0.f, 0.f, 0.f);
  #pragma unroll
  for (int j = 0; j < 4; ++j) {
    int ll = l - 3 + j;
    if (ll >= 0) {
      size_t roff = (((size_t)(b * L_ + ll)) << 10) + c;
      qa = fma4(*(const float4*)(cqwT + (j << 10) + c), *(const float4*)(qpre + roff), qa);
      ka = fma4(*(const float4*)(ckwT + (j << 10) + c), *(const float4*)(kpre + roff), ka);
      va = fma4(*(const float4*)(cvwT + (j << 10) + c), *(const float4*)(vpre + roff), va);
    }
  }
  float4 qv = silu4(qa), kv = silu4(ka), vv = silu4(va);
  *(float4*)(vs + (((size_t)bid) << 10) + c) = vv;
  float sq = qv.x * qv.x + qv.y * qv.y + qv.z * qv.z + qv.w * qv.w;
  float sk = kv.x * kv.x + kv.y * kv.y + kv.z * kv.z + kv.w * kv.w;
  #pragma unroll
  for (int o = 32; o > 0; o >>= 1) {
    sq += __shfl_xor(sq, o, 64);
    sk += __shfl_xor(sk, o, 64);
  }
  float rq = rsqrtf(sq + 1e-6f), rk = rsqrtf(sk + 1e-6f);
  size_t oo = ((((size_t)(b * H_ + h)) * L_ + l) << 8) + (lane << 2);
  float4 qo = make_float4(qv.x * rq, qv.y * rq, qv.z * rq, qv.w * rq);
  float4 ko = make_float4(kv.x * rk, kv.y * rk, kv.z * rk, kv.w * rk);
  *(float4*)(qn + oo) = qo;
  *(float4*)(kn + oo) = ko;
}

// ---------------- per-chunk: inv (fwd-subst, bf16-rounded) + attn + knT + qn_bf ----------------
// kb is applied inline as kn*beta (bit-identical to the previously stored product).
__global__ __launch_bounds__(256) void inv_attn(const float* __restrict__ qn,
    const float* kn, const float* __restrict__ beta,
    float* __restrict__ invb, __hip_bfloat16* __restrict__ att_bf,
    __hip_bfloat16* knT_bf) {
  __shared__ float kn_s[32][257];
  __shared__ float inv_s[32][33];
  __shared__ float bt_s[32];
  int ci = blockIdx.x;
  int t = threadIdx.x;
  size_t base = ((size_t)ci) << 13;
  int bb = ci >> 9, hh = (ci >> 7) & 3, nc = ci & 127;
  if (t < 32) bt_s[t] = beta[(((size_t)(bb * L_ + nc * 32 + t)) << 2) + hh];
  for (int e = t; e < 8192; e += 256) kn_s[e >> 8][e & 255] = kn[base + e];
  __syncthreads();
  {
    unsigned short tmp[32];
    #pragma unroll
    for (int j = 0; j < 32; ++j) tmp[j] = bf16bits(kn_s[j][t]);
    unsigned short* kd = (unsigned short*)knT_bf + (((size_t)ci) << 14) +
                         (size_t)(t >> 4) * 512 + (size_t)(t & 15) * 8;
    #pragma unroll
    for (int g = 0; g < 4; ++g) *(uint4*)(kd + g * 128) = ((const uint4*)tmp)[g];
  }
  {
    int r = t >> 3, kt = t & 7;
    const float4* qrow = (const float4*)(qn + base + (size_t)r * 256 + (kt << 5));
    unsigned short tmp[32];
    #pragma unroll
    for (int i = 0; i < 8; ++i) {
      float4 f = qrow[i];
      tmp[i * 4 + 0] = bf16bits(f.x); tmp[i * 4 + 1] = bf16bits(f.y);
      tmp[i * 4 + 2] = bf16bits(f.z); tmp[i * 4 + 3] = bf16bits(f.w);
    }
    unsigned short* qd = (unsigned short*)knT_bf + (((size_t)ci) << 14) + 8192 +
                         (size_t)(((r >> 4) << 3) + kt) * 512 + (size_t)(r & 15) * 8;
    #pragma unroll
    for (int g = 0; g < 4; ++g) *(uint4*)(qd + g * 128) = ((const uint4*)tmp)[g];
  }
  #pragma unroll
  for (int p = 0; p < 4; ++p) {
    int e = t + (p << 8);
    int i = e >> 5, j = e & 31;
    const float* kni = kn + base + (i << 8);
    const float* qni = qn + base + (i << 8);
    float bti = bt_s[i];
    float am = 0.f, aa = 0.f;
    for (int kk = 0; kk < 256; ++kk) {
      float knv = kn_s[j][kk];
      am += (kni[kk] * bti) * knv;
      aa += qni[kk] * knv;
    }
    inv_s[i][j] = (j < i) ? -am : 0.f;
    ((unsigned short*)att_bf)[((size_t)ci << 10) + (size_t)(i >> 4) * 512 +
        (size_t)((i & 15) + ((j >> 3) << 4)) * 8 + (j & 7)] =
        bf16bits((j <= i) ? aa : 0.f);
  }
  __syncthreads();
  for (int i = 1; i < 32; ++i) {
    float upd = 0.f;
    if (t < i) {
      for (int kk = t + 1; kk < i; ++kk) upd += inv_s[i][kk] * inv_s[kk][t];
    }
    __syncthreads();
    if (t < i) inv_s[i][t] += upd;
    __syncthreads();
  }
  #pragma unroll
  for (int p = 0; p < 4; ++p) {
    int e = t + (p << 8);
    int i = e >> 5, j = e & 31;
    float val = inv_s[i][j] + (i == j ? 1.f : 0.f);
    val = __bfloat162float(__float2bfloat16(val));
    invb[((size_t)ci << 10) + e] = val;
  }
}

// ---------------- u = inv@(vs*beta) -> u_out; w = -(inv@(kn*beta)) as bf16 frag-order ----------------
__global__ __launch_bounds__(256) void uw_kernel(const float* __restrict__ invb,
    const float* __restrict__ vs, const float* __restrict__ kn,
    const float* __restrict__ beta,
    float* __restrict__ u_out, __hip_bfloat16* w_bf) {
  __shared__ float inv_s[32][33];
  __shared__ float tile[32][260];
  __shared__ float bt_s[32];
  int ci = blockIdx.x, t = threadIdx.x;
  size_t base = ((size_t)ci) << 13;
  int bb = ci >> 9, hh = (ci >> 7) & 3, nc = ci & 127;
  size_t vbase = (((size_t)(bb * L_ + nc * 32)) << 10) + (hh << 8);
  for (int e = t; e < 1024; e += 256) inv_s[e >> 5][e & 31] = invb[((size_t)ci << 10) + e];
  if (t < 32) bt_s[t] = beta[(((size_t)(bb * L_ + nc * 32 + t)) << 2) + hh];
  for (int ph = 0; ph < 2; ++ph) {
    __syncthreads();
    for (int f = t; f < 2048; f += 256) {
      int e = f << 2;
      int i = e >> 8, d = e & 255;
      float4 v4;
      if (ph == 0) v4 = *(const float4*)(vs + vbase + (size_t)i * 1024 + d);
      else         v4 = *(const float4*)(kn + base + (i << 8) + d);
      float bt = bt_s[i];
      v4.x *= bt; v4.y *= bt; v4.z *= bt; v4.w *= bt;
      *(float4*)&tile[i][d] = v4;
    }
    __syncthreads();
    int c4 = (t & 63) << 2;
    int ig = t >> 6;
    float4 acc[8];
    #pragma unroll
    for (int ii = 0; ii < 8; ++ii) acc[ii] = make_float4(0.f, 0.f, 0.f, 0.f);
    for (int j = 0; j < 32; ++j) {
      float4 v4 = *(const float4*)&tile[j][c4];
      #pragma unroll
      for (int ii = 0; ii < 8; ++ii) {
        float iv = inv_s[(ig << 3) + ii][j];
        acc[ii].x += iv * v4.x; acc[ii].y += iv * v4.y;
        acc[ii].z += iv * v4.z; acc[ii].w += iv * v4.w;
      }
    }
    #pragma unroll
    for (int ii = 0; ii < 8; ++ii) {
      int i = (ig << 3) + ii;
      if (ph == 0) {
        *(float4*)(u_out + base + (i << 8) + c4) = acc[ii];
      } else {
        ushort4 o;
        o.x = bf16bits(-acc[ii].x); o.y = bf16bits(-acc[ii].y);
        o.z = bf16bits(-acc[ii].z); o.w = bf16bits(-acc[ii].w);
        unsigned short* wd = (unsigned short*)w_bf + (((size_t)ci) << 14) +
            (size_t)(((i >> 4) << 3) + (c4 >> 5)) * 512 +
            (size_t)((i & 15) + (((c4 >> 3) & 3) << 4)) * 8 + (c4 & 7);
        *(ushort4*)wd = o;
      }
    }
  }
}

// ---------------- single-wave MFMA scan, register-direct operands (round-4 best) ----------------
__global__ __launch_bounds__(64, 1) void scan_kernel(
    const __hip_bfloat16* __restrict__ w_bf,
    const __hip_bfloat16* __restrict__ kq_bf,
    const __hip_bfloat16* __restrict__ att_bf,
    const float* __restrict__ u, float* __restrict__ dout) {
  __shared__ __align__(16) unsigned short Sim[2][2][16 * 264];
  __shared__ __align__(16) float UtT[16 * 36];
  int lane = threadIdx.x;
  int mlane = lane & 15, quad = lane >> 4;
  int bh = blockIdx.x & 7;
  int cb = blockIdx.x >> 3;
  int cbase = cb << 4;

  const unsigned short* wbase = (const unsigned short*)w_bf;
  const unsigned short* kqbase = (const unsigned short*)kq_bf;
  const unsigned short* abase = (const unsigned short*)att_bf;

  short8 Wr[16], Qr[16], Kr[16], Ar[2];
  float ur[8], urn[8];

  auto load_WQ = [&](int nc) {
    size_t cb14 = ((size_t)(bh * NCH_ + nc)) << 14;
    const short8* wg = (const short8*)(wbase + cb14 + (size_t)lane * 8);
    const short8* qg = (const short8*)(kqbase + cb14 + 8192 + (size_t)lane * 8);
    #pragma unroll
    for (int s = 0; s < 16; ++s) { Wr[s] = wg[s * 64]; Qr[s] = qg[s * 64]; }
  };
  auto load_K = [&](int nc) {
    size_t cb14 = ((size_t)(bh * NCH_ + nc)) << 14;
    const short8* kg = (const short8*)(kqbase + cb14 + (size_t)lane * 8);
    #pragma unroll
    for (int s = 0; s < 16; ++s) Kr[s] = kg[s * 64];
  };
  auto load_A = [&](int nc) {
    const short8* ag = (const short8*)(abase + (((size_t)(bh * NCH_ + nc)) << 10) +
                                       (size_t)lane * 8);
    Ar[0] = ag[0]; Ar[1] = ag[64];
  };
  auto load_u8 = [&](int nc, float* dst) {
    size_t cbf = ((size_t)(bh * NCH_ + nc)) << 13;
    const float* up = u + cbf + (size_t)(quad * 4) * 256 + cbase + mlane;
    #pragma unroll
    for (int tt = 0; tt < 2; ++tt)
      #pragma unroll
      for (int r = 0; r < 4; ++r) dst[tt * 4 + r] = up[(tt * 16 + r) * 256];
  };

  for (int e = lane; e < 16 * 264; e += 64) { Sim[0][0][e] = 0; Sim[0][1][e] = 0; }
  f32x4 accS[16];
  #pragma unroll
  for (int i = 0; i < 16; ++i) accS[i] = (f32x4){0.f, 0.f, 0.f, 0.f};

  load_WQ(0);
  load_K(0);
  load_A(0);
  load_u8(0, ur);

  for (int nc = 0; nc < NCH_; ++nc) {
    int cur = nc & 1, alt = cur ^ 1;
    int nn = nc + 1 < NCH_ ? nc + 1 : NCH_ - 1;

    f32x4 uh0 = (f32x4){ur[0], ur[1], ur[2], ur[3]};
    f32x4 uh1 = (f32x4){ur[4], ur[5], ur[6], ur[7]};
    f32x4 ul0 = (f32x4){0.f, 0.f, 0.f, 0.f}, ul1 = (f32x4){0.f, 0.f, 0.f, 0.f};
    f32x4 oh0 = (f32x4){0.f, 0.f, 0.f, 0.f}, oh1 = (f32x4){0.f, 0.f, 0.f, 0.f};
    f32x4 ol0 = (f32x4){0.f, 0.f, 0.f, 0.f}, ol1 = (f32x4){0.f, 0.f, 0.f, 0.f};
    #pragma unroll
    for (int kt = 0; kt < 8; ++kt) {
      short8 bhi = *(const short8*)&Sim[cur][0][mlane * 264 + kt * 32 + quad * 8];
      short8 blo = *(const short8*)&Sim[cur][1][mlane * 264 + kt * 32 + quad * 8];
      uh0 = __builtin_amdgcn_mfma_f32_16x16x32_bf16(Wr[kt], bhi, uh0, 0, 0, 0);
      ul0 = __builtin_amdgcn_mfma_f32_16x16x32_bf16(Wr[kt], blo, ul0, 0, 0, 0);
      uh1 = __builtin_amdgcn_mfma_f32_16x16x32_bf16(Wr[8 + kt], bhi, uh1, 0, 0, 0);
      ul1 = __builtin_amdgcn_mfma_f32_16x16x32_bf16(Wr[8 + kt], blo, ul1, 0, 0, 0);
      oh0 = __builtin_amdgcn_mfma_f32_16x16x32_bf16(Qr[kt], bhi, oh0, 0, 0, 0);
      ol0 = __builtin_amdgcn_mfma_f32_16x16x32_bf16(Qr[kt], blo, ol0, 0, 0, 0);
      oh1 = __builtin_amdgcn_mfma_f32_16x16x32_bf16(Qr[8 + kt], bhi, oh1, 0, 0, 0);
      ol1 = __builtin_amdgcn_mfma_f32_16x16x32_bf16(Qr[8 + kt], blo, ol1, 0, 0, 0);
    }
    f32x4 ut0 = uh0 + ul0, ut1 = uh1 + ul1;
    *(f32x4*)&UtT[mlane * 36 + quad * 4] = ut0;
    *(f32x4*)&UtT[mlane * 36 + 16 + quad * 4] = ut1;
    load_WQ(nn);
    load_u8(nn, urn);
    short8 but;
    {
      const float* up = &UtT[mlane * 36 + quad * 8];
      #pragma unroll
      for (int j = 0; j < 8; ++j) but[j] = (short)bf16bits(up[j]);
    }
    f32x4 o0 = oh0 + ol0, o1 = oh1 + ol1;
    o0 = __builtin_amdgcn_mfma_f32_16x16x32_bf16(Ar[0], but, o0, 0, 0, 0);
    o1 = __builtin_amdgcn_mfma_f32_16x16x32_bf16(Ar[1], but, o1, 0, 0, 0);
    load_A(nn);
    size_t cbf = ((size_t)(bh * NCH_ + nc)) << 13;
    float* op = dout + cbf + (size_t)(quad * 4) * 256 + cbase + mlane;
    #pragma unroll
    for (int r = 0; r < 4; ++r) { op[r * 256] = o0[r]; op[(16 + r) * 256] = o1[r]; }
    #pragma unroll
    for (int t2 = 0; t2 < 16; ++t2) {
      accS[t2] = __builtin_amdgcn_mfma_f32_16x16x32_bf16(Kr[t2], but, accS[t2], 0, 0, 0);
      unsigned short nh[4], nl[4];
      #pragma unroll
      for (int r = 0; r < 4; ++r) {
        float sv = accS[t2][r];
        unsigned short hb = bf16bits(sv);
        nh[r] = hb;
        nl[r] = bf16bits(sv - bits2f(hb));
      }
      *(uint2*)&Sim[alt][0][mlane * 264 + t2 * 16 + quad * 4] = *(const uint2*)nh;
      *(uint2*)&Sim[alt][1][mlane * 264 + t2 * 16 + quad * 4] = *(const uint2*)nl;
    }
    load_K(nn);
    #pragma unroll
    for (int r = 0; r < 8; ++r) ur[r] = urn[r];
  }
}

// ---------------- gate: NL=8 tokens/block; shared qg-matvec hoisted to qgH GEMM ----------------
__global__ __launch_bounds__(256, 1) void gate_kernel(
    const float* __restrict__ v, const float* __restrict__ delta,
    const float* __restrict__ qgH,
    const float* __restrict__ fw0, const float* __restrict__ fw1T,
    const float* __restrict__ fw2T, const float* __restrict__ fw3T,
    const float* __restrict__ Wf1, const float* __restrict__ Wf2,
    const float* __restrict__ bf1, const float* __restrict__ bf2,
    const float* __restrict__ ltm, const float* __restrict__ onw,
    __hip_bfloat16* __restrict__ obf) {
  __shared__ float W1t[6][136];   // Wf1 rows 128..133 (summary tail)
  __shared__ float W2f[804];      // Wf2 [134][6] flat
  __shared__ float bf1s[136];
  int t = threadIdx.x;
  int wave = t >> 6, lane = t & 63;
  for (int e = t; e < 804; e += 256) {
    int s = e / 134, u = e - s * 134;
    W1t[s][u] = Wf1[(128 + s) * GH_c + u];
    W2f[e] = Wf2[e];
  }
  if (t < GH_c) bf1s[t] = bf1[t];
  __syncthreads();

  int bid = blockIdx.x;
  int bl0 = (((bid & 7) << 7) | (bid >> 3)) << 3;   // 1024 blocks -> 8 tokens each
  int b = bl0 >> 12;
  int h = wave;
  int c = (h << 8) + (lane << 2);

  float4 fw3r[15], fw2r[7], fw1r[3], fw0r;
  #pragma unroll
  for (int j = 0; j < 15; ++j) fw3r[j] = *(const float4*)(fw3T + (j << 10) + c);
  #pragma unroll
  for (int j = 0; j < 7; ++j) fw2r[j] = *(const float4*)(fw2T + (j << 10) + c);
  #pragma unroll
  for (int j = 0; j < 3; ++j) fw1r[j] = *(const float4*)(fw1T + (j << 10) + c);
  fw0r = *(const float4*)(fw0 + c);
  float4 ow = *(const float4*)(onw + (lane << 2));
  float itemp = expf(ltm[h]);
  float b2r[6];
  #pragma unroll
  for (int s = 0; s < 6; ++s) b2r[s] = bf2[s];
  int u3 = 128 + (lane < 6 ? lane : 0);

  auto gelu = [](float a) -> float {
    return 0.5f * a * (1.f + erff(a * 0.70710678f));
  };

  for (int tk = 0; tk < 8; ++tk) {
    int bl = bl0 + tk;
    int l = bl & (L_ - 1);
    float4 st0, st1, st2, st3, st4, st5;
    st1 = make_float4(0, 0, 0, 0);
    st2 = make_float4(0, 0, 0, 0);
    st3 = make_float4(0, 0, 0, 0);
    #pragma unroll
    for (int j = 0; j < 15; ++j) {
      int ll = l - 14 + j;
      float4 vj = make_float4(0, 0, 0, 0);
      if (ll >= 0) vj = *(const float4*)(v + ((((size_t)(b * L_ + ll)) << 10) + c));
      st3 = fma4(fw3r[j], vj, st3);
      if (j >= 8) st2 = fma4(fw2r[j - 8], vj, st2);
      if (j >= 12) st1 = fma4(fw1r[j - 12], vj, st1);
      if (j == 14) {
        st0 = make_float4(fw0r.x * vj.x, fw0r.y * vj.y, fw0r.z * vj.z, fw0r.w * vj.w);
        st5 = vj;
      }
    }
    st4 = *(const float4*)(delta + ((((size_t)((b * H_ + h) * L_ + l)) << 8) + (lane << 2)));

    float s0 = st0.x + st0.y + st0.z + st0.w;
    float s1 = st1.x + st1.y + st1.z + st1.w;
    float s2 = st2.x + st2.y + st2.z + st2.w;
    float s3 = st3.x + st3.y + st3.z + st3.w;
    float s4 = st4.x + st4.y + st4.z + st4.w;
    float s5 = st5.x + st5.y + st5.z + st5.w;
    #pragma unroll
    for (int o = 32; o > 0; o >>= 1) {
      s0 += __shfl_down(s0, o, 64); s1 += __shfl_down(s1, o, 64);
      s2 += __shfl_down(s2, o, 64); s3 += __shfl_down(s3, o, 64);
      s4 += __shfl_down(s4, o, 64); s5 += __shfl_down(s5, o, 64);
    }
    float ss_[6];
    ss_[0] = __shfl(s0, 0, 64) * (1.f / 256.f);
    ss_[1] = __shfl(s1, 0, 64) * (1.f / 256.f);
    ss_[2] = __shfl(s2, 0, 64) * (1.f / 256.f);
    ss_[3] = __shfl(s3, 0, 64) * (1.f / 256.f);
    ss_[4] = __shfl(s4, 0, 64) * (1.f / 256.f);
    ss_[5] = __shfl(s5, 0, 64) * (1.f / 256.f);

    const float* qr = qgH + ((size_t)bl << 8);
    float a0 = qr[lane] + bf1s[lane];
    float a1 = qr[64 + lane] + bf1s[64 + lane];
    float a2 = qr[u3] + bf1s[u3];
    #pragma unroll
    for (int s = 0; s < 6; ++s) {
      a0 = fmaf(W1t[s][lane], ss_[s], a0);
      a1 = fmaf(W1t[s][64 + lane], ss_[s], a1);
      a2 = fmaf(W1t[s][u3], ss_[s], a2);
    }
    float h0 = gelu(a0);
    float h1 = gelu(a1);
    float h2 = (lane < 6) ? gelu(a2) : 0.f;

    const float* w2a = W2f + lane * 6;
    const float* w2b = W2f + (64 + lane) * 6;
    const float* w2c = W2f + u3 * 6;
    float t0 = h0 * w2a[0] + h1 * w2b[0] + h2 * w2c[0];
    float t1 = h0 * w2a[1] + h1 * w2b[1] + h2 * w2c[1];
    float t2 = h0 * w2a[2] + h1 * w2b[2] + h2 * w2c[2];
    float t3 = h0 * w2a[3] + h1 * w2b[3] + h2 * w2c[3];
    float t4 = h0 * w2a[4] + h1 * w2b[4] + h2 * w2c[4];
    float t5 = h0 * w2a[5] + h1 * w2b[5] + h2 * w2c[5];
    #pragma unroll
    for (int o = 32; o > 0; o >>= 1) {
      t0 += __shfl_down(t0, o, 64); t1 += __shfl_down(t1, o, 64);
      t2 += __shfl_down(t2, o, 64); t3 += __shfl_down(t3, o, 64);
      t4 += __shfl_down(t4, o, 64); t5 += __shfl_down(t5, o, 64);
    }
    float p0, p1, p2, p3, p4, p5;
    if (lane == 0) {
      float l0v = (t0 + b2r[0]) / itemp, l1v = (t1 + b2r[1]) / itemp;
      float l2v = (t2 + b2r[2]) / itemp, l3v = (t3 + b2r[3]) / itemp;
      float l4v = (t4 + b2r[4]) / itemp, l5v = (t5 + b2r[5]) / itemp;
      float m = fmaxf(fmaxf(fmaxf(l0v, l1v), fmaxf(l2v, l3v)), fmaxf(l4v, l5v));
      float e0 = expf(l0v - m), e1 = expf(l1v - m), e2 = expf(l2v - m);
      float e3 = expf(l3v - m), e4 = expf(l4v - m), e5 = expf(l5v - m);
      float inv = 1.f / (e0 + e1 + e2 + e3 + e4 + e5);
      p0 = e0 * inv * 0.88f + 0.02f; p1 = e1 * inv * 0.88f + 0.02f;
      p2 = e2 * inv * 0.88f + 0.02f; p3 = e3 * inv * 0.88f + 0.02f;
      p4 = e4 * inv * 0.88f + 0.02f; p5 = e5 * inv * 0.88f + 0.02f;
    }
    p0 = __shfl(p0, 0, 64); p1 = __shfl(p1, 0, 64); p2 = __shfl(p2, 0, 64);
    p3 = __shfl(p3, 0, 64); p4 = __shfl(p4, 0, 64); p5 = __shfl(p5, 0, 64);

    float4 fu;
    fu.x = p0 * st0.x + p1 * st1.x + p2 * st2.x + p3 * st3.x + p4 * st4.x + p5 * st5.x;
    fu.y = p0 * st0.y + p1 * st1.y + p2 * st2.y + p3 * st3.y + p4 * st4.y + p5 * st5.y;
    fu.z = p0 * st0.z + p1 * st1.z + p2 * st2.z + p3 * st3.z + p4 * st4.z + p5 * st5.z;
    fu.w = p0 * st0.w + p1 * st1.w + p2 * st2.w + p3 * st3.w + p4 * st4.w + p5 * st5.w;
    float ssq = fu.x * fu.x + fu.y * fu.y + fu.z * fu.z + fu.w * fu.w;
    #pragma unroll
    for (int o = 32; o > 0; o >>= 1) ssq += __shfl_xor(ssq, o, 64);
    float sc = rsqrtf(ssq * (1.f / 256.f) + 1e-5f);
    ushort4 ob;
    ob.x = bf16bits(fu.x * sc * ow.x);
    ob.y = bf16bits(fu.y * sc * ow.y);
    ob.z = bf16bits(fu.z * sc * ow.z);
    ob.w = bf16bits(fu.w * sc * ow.w);
    *(ushort4*)((unsigned short*)obf + (((size_t)bl) << 10) + c) = ob;
  }
}

// ---------------- launch ----------------
extern "C" void kernel_launch(void* const* d_in, const int* in_sizes, int n_in,
                              void* d_out, int out_size, void* d_ws, size_t ws_size,
                              hipStream_t stream) {
  const float* x   = (const float*)d_in[0];
  const float* Wq  = (const float*)d_in[1];
  const float* Wk  = (const float*)d_in[2];
  const float* Wv  = (const float*)d_in[3];
  const float* Wb  = (const float*)d_in[4];
  const float* cqw = (const float*)d_in[5];
  const float* ckw = (const float*)d_in[6];
  const float* cvw = (const float*)d_in[7];
  const float* fw0 = (const float*)d_in[8];
  const float* fw1 = (const float*)d_in[9];
  const float* fw2 = (const float*)d_in[10];
  const float* fw3 = (const float*)d_in[11];
  const float* Wqg = (const float*)d_in[12];
  const float* bqg = (const float*)d_in[13];
  const float* Wf1 = (const float*)d_in[14];
  const float* bf1 = (const float*)d_in[15];
  const float* Wf2 = (const float*)d_in[16];
  const float* bf2 = (const float*)d_in[17];
  const float* ltm = (const float*)d_in[18];
  const float* onw = (const float*)d_in[19];
  const float* Wo  = (const float*)d_in[20];
  float* out = (float*)d_out;
  float* ws = (float*)d_ws;

  const size_t BIG = (size_t)BL_ * C_;
  float* qpre = ws;                 // GEMM q out -> gate_bf after gate
  float* kpre = ws + BIG;           // GEMM k out -> knT_bf+qn_bf (frag-order)
  float* vpre = ws + 2 * BIG;       // GEMM v out -> u f32 (uw output)
  float* qs   = ws + 3 * BIG;       // x_bf early -> qn f32 -> delta_out (scan)
  float* ks   = ws + 4 * BIG;       // kn f32 -> qgH/qg_bf/wf1qT after uw
  float* vs   = ws + 5 * BIG;       // v_direct (fused conv out, gate FIR input)
  float* kbw  = ws + 6 * BIG;       // wT bf16 early -> w_bf (frag-order) -> woT
  float* invb = ws + 7 * BIG;
  float* attb = invb + (size_t)1024 * 1024;
  float* beta = attb + (size_t)1024 * 1024;
  float* qg   = beta + (size_t)BL_ * H_;

  __hip_bfloat16* x_bf  = (__hip_bfloat16*)qs;
  __hip_bfloat16* wqT   = (__hip_bfloat16*)kbw;
  __hip_bfloat16* wkT   = wqT + (size_t)1024 * 1024;
  __hip_bfloat16* wvT   = wkT + (size_t)1024 * 1024;
  __hip_bfloat16* wqgT  = wvT + (size_t)1024 * 1024;
  __hip_bfloat16* woT   = (__hip_bfloat16*)kbw;
  __hip_bfloat16* gate_bf = (__hip_bfloat16*)qpre;
  __hip_bfloat16* knT_bf = (__hip_bfloat16*)kpre;   // + qn_bf in slot second halves
  __hip_bfloat16* w_bf   = (__hip_bfloat16*)kbw;
  __hip_bfloat16* att_bf = (__hip_bfloat16*)attb;
  float* scr   = attb + (size_t)600000;
  float* fw1T  = scr;
  float* fw2T  = scr + 3072;
  float* fw3T  = scr + 10240;
  float* cqwT  = scr + 25600;       // [4][1024] transposed conv weights
  float* ckwT  = scr + 29696;
  float* cvwT  = scr + 33792;

  float* qgH = ks;                                            // 8192 x 256 f32 (after uw)
  __hip_bfloat16* qg_bf  = (__hip_bfloat16*)(ks + (size_t)3 * 1024 * 1024);
  __hip_bfloat16* wf1qT  = (__hip_bfloat16*)(ks + (size_t)4 * 1024 * 1024);

  dim3 blk(256);
  f32_to_bf16_k<<<dim3(BL_ * D_ / 1024), blk, 0, stream>>>(x, x_bf);
  transpose_bf16<<<dim3(32, 32), blk, 0, stream>>>(Wq, wqT, D_, C_);
  transpose_bf16<<<dim3(32, 32), blk, 0, stream>>>(Wk, wkT, D_, C_);
  transpose_bf16<<<dim3(32, 32), blk, 0, stream>>>(Wv, wvT, D_, C_);
  transpose_bf16<<<dim3(4, 32), blk, 0, stream>>>(Wqg, wqgT, D_, GQP_c);
  small_transpose<<<dim3(16), blk, 0, stream>>>(fw1, fw1T, 1024, 3, 1024);
  small_transpose<<<dim3(32), blk, 0, stream>>>(fw2, fw2T, 1024, 7, 1024);
  small_transpose<<<dim3(64), blk, 0, stream>>>(fw3, fw3T, 1024, 15, 1024);
  conv_prep<<<dim3(16), blk, 0, stream>>>(cqw, cqwT);
  conv_prep<<<dim3(16), blk, 0, stream>>>(ckw, ckwT);
  conv_prep<<<dim3(16), blk, 0, stream>>>(cvw, cvwT);
  gemm_bf16<<<dim3(8, 64), blk, 0, stream>>>(x_bf, wqT, nullptr, qpre, BL_, C_, D_);
  gemm_bf16<<<dim3(8, 64), blk, 0, stream>>>(x_bf, wkT, nullptr, kpre, BL_, C_, D_);
  gemm_bf16<<<dim3(8, 64), blk, 0, stream>>>(x_bf, wvT, nullptr, vpre, BL_, C_, D_);
  gemm_bf16<<<dim3(1, 64), blk, 0, stream>>>(x_bf, wqgT, bqg, qg, BL_, GQP_c, D_);
  beta_kernel<<<dim3(BL_), blk, 0, stream>>>(x, Wb, beta);
  // fused conv+silu+l2norm+transpose (overwrites x_bf in qs with qn; writes kn->ks, vs)
  conv_norm_fused<<<dim3(BL_), blk, 0, stream>>>(qpre, kpre, vpre, cqwT, ckwT, cvwT,
                                                 vs, qs, ks);
  inv_attn<<<dim3(1024), blk, 0, stream>>>(qs, ks, beta, invb, att_bf, knT_bf);
  uw_kernel<<<dim3(1024), blk, 0, stream>>>(invb, vs, ks, beta, vpre, w_bf);
  // ks slot now free: build qgH = qg @ Wf1[0:128,:] (bf16 MFMA, f32 accum)
  f32_to_bf16_k<<<dim3(BL_ * GQP_c / 1024), blk, 0, stream>>>(qg, qg_bf);
  wf1q_prep<<<dim3(128), blk, 0, stream>>>(Wf1, wf1qT);
  gemm_bf16<<<dim3(2, 64), blk, 0, stream>>>(qg_bf, wf1qT, nullptr, qgH, BL_, 256, 128);
  scan_kernel<<<dim3(128), dim3(64), 0, stream>>>(w_bf, knT_bf, att_bf, vpre, qs);
  transpose_bf16<<<dim3(32, 32), blk, 0, stream>>>(Wo, woT, C_, D_);
  gate_kernel<<<dim3(1024), blk, 0, stream>>>(vs, qs, qgH, fw0, fw1T, fw2T, fw3T,
                                              Wf1, Wf2, bf1, bf2, ltm, onw, gate_bf);
  gemm_bf16<<<dim3(8, 64), blk, 0, stream>>>(gate_bf, woT, nullptr, out, BL_, D_, C_);
}

// Round 11
// 885.999 us; speedup vs baseline: 1.2216x; 1.0022x over previous
//
#include <hip/hip_runtime.h>
#include <hip/hip_bf16.h>
#include <math.h>

#define B_ 2
#define L_ 4096
#define D_ 1024
#define H_ 4
#define DK_ 256
#define BL_ 8192
#define C_ 1024
#define NCH_ 128
#define GQP_c 128
#define NS_c 6
#define GIN_c 134
#define GH_c 134

typedef __attribute__((ext_vector_type(8))) short short8;
typedef __attribute__((ext_vector_type(4))) float f32x4;

// ---------------- helpers ----------------
__device__ __forceinline__ unsigned short bf16bits(float f) {
  __hip_bfloat16 h = __float2bfloat16(f);
  return *(unsigned short*)&h;
}

__device__ __forceinline__ float bits2f(unsigned short u) {
  unsigned int x = ((unsigned int)u) << 16;
  return *(float*)&x;
}

__device__ __forceinline__ float4 fma4(float4 a, float4 b, float4 c) {
  return make_float4(fmaf(a.x, b.x, c.x), fmaf(a.y, b.y, c.y),
                     fmaf(a.z, b.z, c.z), fmaf(a.w, b.w, c.w));
}

__device__ __forceinline__ float4 silu4(float4 a) {
  return make_float4(a.x / (1.f + expf(-a.x)), a.y / (1.f + expf(-a.y)),
                     a.z / (1.f + expf(-a.z)), a.w / (1.f + expf(-a.w)));
}

__device__ __forceinline__ void gload_lds16(const void* g, void* l) {
  __builtin_amdgcn_global_load_lds(
      (const __attribute__((address_space(1))) void*)g,
      (__attribute__((address_space(3))) void*)l, 16, 0, 0);
}

// ---------------- f32 -> bf16 convert ----------------
__global__ __launch_bounds__(256) void f32_to_bf16_k(const float* __restrict__ in,
    __hip_bfloat16* __restrict__ out) {
  size_t i = ((size_t)blockIdx.x * 256 + threadIdx.x) << 2;
  float4 v = *(const float4*)(in + i);
  ushort4 o;
  o.x = bf16bits(v.x); o.y = bf16bits(v.y); o.z = bf16bits(v.z); o.w = bf16bits(v.w);
  *(ushort4*)((unsigned short*)out + i) = o;
}

// ---------------- transpose W(K,N) f32 -> WT(N,K) bf16 ----------------
__global__ __launch_bounds__(256) void transpose_bf16(const float* __restrict__ W,
    __hip_bfloat16* __restrict__ WT, int K, int N) {
  __shared__ float tile[32][33];
  int t = threadIdx.x;
  int r = t >> 3, c4 = (t & 7) << 2;
  int n0 = blockIdx.x << 5, k0 = blockIdx.y << 5;
  float4 v = *(const float4*)(W + (size_t)(k0 + r) * N + n0 + c4);
  tile[r][c4] = v.x; tile[r][c4 + 1] = v.y; tile[r][c4 + 2] = v.z; tile[r][c4 + 3] = v.w;
  __syncthreads();
  ushort4 o;
  o.x = bf16bits(tile[c4][r]);
  o.y = bf16bits(tile[c4 + 1][r]);
  o.z = bf16bits(tile[c4 + 2][r]);
  o.w = bf16bits(tile[c4 + 3][r]);
  *(ushort4*)((unsigned short*)WT + (size_t)(n0 + r) * K + k0 + c4) = o;
}

// ---------------- small f32 transpose with zero-pad: out[c*OS+r] = in[r*Cc+c] ----------------
__global__ __launch_bounds__(256) void small_transpose(const float* __restrict__ in,
    float* __restrict__ out, int R, int Cc, int OS) {
  int total = Cc * OS;
  for (int e = blockIdx.x * 256 + threadIdx.x; e < total; e += gridDim.x * 256) {
    int cIdx = e / OS, r = e - cIdx * OS;
    out[e] = (r < R) ? in[(size_t)r * Cc + cIdx] : 0.f;
  }
}

// ---------------- Wf1 qg-part -> bf16 BT layout [256 rows][K=128] ----------------
__global__ __launch_bounds__(256) void wf1q_prep(const float* __restrict__ Wf1,
    __hip_bfloat16* __restrict__ out) {
  int idx = blockIdx.x * 256 + threadIdx.x;   // 256*128 = 32768 total
  int u = idx >> 7, i = idx & 127;
  float val = (u < GH_c) ? Wf1[i * GH_c + u] : 0.f;
  out[idx] = __float2bfloat16(val);
}

// ---------------- conv weight transpose: cw[1024][4] -> cwT[4][1024] ----------------
__global__ __launch_bounds__(256) void conv_prep(const float* __restrict__ cw,
    float* __restrict__ cwT) {
  int t = blockIdx.x * 256 + threadIdx.x;   // 4096 total
  int j = t >> 10, c = t & (C_ - 1);
  cwT[t] = cw[(c << 2) + j];
}

// ---------------- bf16 MFMA GEMM (m97 structure, XCD-chunked block swizzle) ----------------
// nwg must be divisible by 8 (all call sites: 512/128). The chunked remap gives
// each XCD a contiguous run of M-panels with the full N sweep -> A panels are
// fetched once per XCD instead of 8x; B (<=2MB) stays L2-resident.
__global__ __launch_bounds__(256) void gemm_bf16(
    const __hip_bfloat16* __restrict__ A, const __hip_bfloat16* __restrict__ BT,
    const float* __restrict__ bias, float* __restrict__ C, int M, int N, int K) {
  __shared__ __align__(16) __hip_bfloat16 Asm[4096];
  __shared__ __align__(16) __hip_bfloat16 Bsm[4096];
  int tid = threadIdx.x;
  int lane = tid & 63, wave = tid >> 6;
  int wm = wave >> 1, wn = wave & 1;
  int nwg = gridDim.x * gridDim.y;
  int id = blockIdx.y * gridDim.x + blockIdx.x;
  int swz = (id & 7) * (nwg >> 3) + (id >> 3);
  int bx = swz % gridDim.x, by = swz / gridDim.x;
  int rowBase = by * 128, colBase = bx * 128;
  f32x4 acc[4][4];
  #pragma unroll
  for (int i = 0; i < 4; ++i)
    #pragma unroll
    for (int j = 0; j < 4; ++j) acc[i][j] = (f32x4){0.f, 0.f, 0.f, 0.f};

  for (int kt = 0; kt < K; kt += 32) {
    __syncthreads();
    #pragma unroll
    for (int it = 0; it < 2; ++it) {
      int s = tid + (it << 8);
      int T = s >> 6, q = (s >> 4) & 3, m = s & 15;
      const __hip_bfloat16* ga = A + (size_t)(rowBase + T * 16 + m) * K + kt + q * 8;
      gload_lds16(ga, Asm + s * 8);
      const __hip_bfloat16* gb = BT + (size_t)(colBase + T * 16 + m) * K + kt + q * 8;
      gload_lds16(gb, Bsm + s * 8);
    }
    __syncthreads();
    short8 af[4], bfr[4];
    #pragma unroll
    for (int i = 0; i < 4; ++i) {
      af[i]  = *(const short8*)(Asm + ((wm * 4 + i) << 9) + lane * 8);
      bfr[i] = *(const short8*)(Bsm + ((wn * 4 + i) << 9) + lane * 8);
    }
    #pragma unroll
    for (int i = 0; i < 4; ++i)
      #pragma unroll
      for (int j = 0; j < 4; ++j)
        acc[i][j] = __builtin_amdgcn_mfma_f32_16x16x32_bf16(af[i], bfr[j], acc[i][j], 0, 0, 0);
  }
  int r0 = (lane >> 4) * 4, c0 = lane & 15;
  #pragma unroll
  for (int i = 0; i < 4; ++i) {
    int row = rowBase + (wm * 4 + i) * 16 + r0;
    #pragma unroll
    for (int j = 0; j < 4; ++j) {
      int col = colBase + (wn * 4 + j) * 16 + c0;
      float bs = bias ? bias[col] : 0.f;
      #pragma unroll
      for (int r = 0; r < 4; ++r)
        C[(size_t)(row + r) * N + col] = acc[i][j][r] + bs;
    }
  }
}

// ---------------- beta = sigmoid(x @ Wb) ----------------
__global__ __launch_bounds__(256) void beta_kernel(const float* __restrict__ x,
    const float* __restrict__ Wb, float* __restrict__ beta) {
  int row = blockIdx.x;
  int t = threadIdx.x;
  int h = t >> 6, lane = t & 63;
  const float* xr = x + (size_t)row * D_;
  float acc = 0.f;
  for (int k = lane; k < D_; k += 64) acc += xr[k] * Wb[(k << 2) + h];
  #pragma unroll
  for (int o = 32; o > 0; o >>= 1) acc += __shfl_down(acc, o, 64);
  if (lane == 0) beta[(row << 2) + h] = 1.f / (1.f + expf(-acc));
}

// ---------------- fused conv(K=4)+SiLU + l2norm + BLHD->BHLD transpose ----------------
__global__ __launch_bounds__(256) void conv_norm_fused(
    const float* __restrict__ qpre, const float* __restrict__ kpre,
    const float* __restrict__ vpre,
    const float* __restrict__ cqwT, const float* __restrict__ ckwT,
    const float* __restrict__ cvwT,
    float* __restrict__ vs, float* __restrict__ qn, float* __restrict__ kn) {
  int bid = blockIdx.x;             // b*L + l
  int b = bid >> 12, l = bid & (L_ - 1);
  int t = threadIdx.x;
  int h = t >> 6, lane = t & 63;
  int c = t << 2;
  float4 qa = make_float4(0.f, 0.f, 0.f, 0.f);
  float4 ka = make_float4(0.f, 0.f, 0.f, 0.f);
  float4 va = make_float4(0.f, 0.f, 0.f, 0.f);
  #pragma unroll
  for (int j = 0; j < 4; ++j) {
    int ll = l - 3 + j;
    if (ll >= 0) {
      size_t roff = (((size_t)(b * L_ + ll)) << 10) + c;
      qa = fma4(*(const float4*)(cqwT + (j << 10) + c), *(const float4*)(qpre + roff), qa);
      ka = fma4(*(const float4*)(ckwT + (j << 10) + c), *(const float4*)(kpre + roff), ka);
      va = fma4(*(const float4*)(cvwT + (j << 10) + c), *(const float4*)(vpre + roff), va);
    }
  }
  float4 qv = silu4(qa), kv = silu4(ka), vv = silu4(va);
  *(float4*)(vs + (((size_t)bid) << 10) + c) = vv;
  float sq = qv.x * qv.x + qv.y * qv.y + qv.z * qv.z + qv.w * qv.w;
  float sk = kv.x * kv.x + kv.y * kv.y + kv.z * kv.z + kv.w * kv.w;
  #pragma unroll
  for (int o = 32; o > 0; o >>= 1) {
    sq += __shfl_xor(sq, o, 64);
    sk += __shfl_xor(sk, o, 64);
  }
  float rq = rsqrtf(sq + 1e-6f), rk = rsqrtf(sk + 1e-6f);
  size_t oo = ((((size_t)(b * H_ + h)) * L_ + l) << 8) + (lane << 2);
  float4 qo = make_float4(qv.x * rq, qv.y * rq, qv.z * rq, qv.w * rq);
  float4 ko = make_float4(kv.x * rk, kv.y * rk, kv.z * rk, kv.w * rk);
  *(float4*)(qn + oo) = qo;
  *(float4*)(kn + oo) = ko;
}

// ---------------- per-chunk: inv (fwd-subst, bf16-rounded) + attn + knT + qn_bf ----------------
// kb is applied inline as kn*beta (bit-identical product). am/aa dot products
// vectorized float4 (kn_s rows padded to 260 for aligned ds_read_b128; 4-way
// bank conflict but 4x fewer issue slots). Accumulation order changes only in
// fp32 (4 partial sums) -- attn is bf16-rounded immediately; inv perturbation
// ~1e-7 relative, << bf16 ulp.
__global__ __launch_bounds__(256) void inv_attn(const float* __restrict__ qn,
    const float* kn, const float* __restrict__ beta,
    float* __restrict__ invb, __hip_bfloat16* __restrict__ att_bf,
    __hip_bfloat16* knT_bf) {
  __shared__ __align__(16) float kn_s[32][260];
  __shared__ float inv_s[32][33];
  __shared__ float bt_s[32];
  int ci = blockIdx.x;
  int t = threadIdx.x;
  size_t base = ((size_t)ci) << 13;
  int bb = ci >> 9, hh = (ci >> 7) & 3, nc = ci & 127;
  if (t < 32) bt_s[t] = beta[(((size_t)(bb * L_ + nc * 32 + t)) << 2) + hh];
  for (int e = t; e < 8192; e += 256) kn_s[e >> 8][e & 255] = kn[base + e];
  __syncthreads();
  {
    unsigned short tmp[32];
    #pragma unroll
    for (int j = 0; j < 32; ++j) tmp[j] = bf16bits(kn_s[j][t]);
    unsigned short* kd = (unsigned short*)knT_bf + (((size_t)ci) << 14) +
                         (size_t)(t >> 4) * 512 + (size_t)(t & 15) * 8;
    #pragma unroll
    for (int g = 0; g < 4; ++g) *(uint4*)(kd + g * 128) = ((const uint4*)tmp)[g];
  }
  {
    int r = t >> 3, kt = t & 7;
    const float4* qrow = (const float4*)(qn + base + (size_t)r * 256 + (kt << 5));
    unsigned short tmp[32];
    #pragma unroll
    for (int i = 0; i < 8; ++i) {
      float4 f = qrow[i];
      tmp[i * 4 + 0] = bf16bits(f.x); tmp[i * 4 + 1] = bf16bits(f.y);
      tmp[i * 4 + 2] = bf16bits(f.z); tmp[i * 4 + 3] = bf16bits(f.w);
    }
    unsigned short* qd = (unsigned short*)knT_bf + (((size_t)ci) << 14) + 8192 +
                         (size_t)(((r >> 4) << 3) + kt) * 512 + (size_t)(r & 15) * 8;
    #pragma unroll
    for (int g = 0; g < 4; ++g) *(uint4*)(qd + g * 128) = ((const uint4*)tmp)[g];
  }
  #pragma unroll
  for (int p = 0; p < 4; ++p) {
    int e = t + (p << 8);
    int i = e >> 5, j = e & 31;
    const float* kni = kn + base + (i << 8);
    const float* qni = qn + base + (i << 8);
    float bti = bt_s[i];
    float4 am4 = make_float4(0.f, 0.f, 0.f, 0.f);
    float4 aa4 = make_float4(0.f, 0.f, 0.f, 0.f);
    for (int kk = 0; kk < 256; kk += 4) {
      float4 kn4 = *(const float4*)&kn_s[j][kk];
      float4 kb4 = *(const float4*)(kni + kk);
      float4 qn4 = *(const float4*)(qni + kk);
      kb4.x *= bti; kb4.y *= bti; kb4.z *= bti; kb4.w *= bti;
      am4 = fma4(kb4, kn4, am4);
      aa4 = fma4(qn4, kn4, aa4);
    }
    float am = (am4.x + am4.y) + (am4.z + am4.w);
    float aa = (aa4.x + aa4.y) + (aa4.z + aa4.w);
    inv_s[i][j] = (j < i) ? -am : 0.f;
    ((unsigned short*)att_bf)[((size_t)ci << 10) + (size_t)(i >> 4) * 512 +
        (size_t)((i & 15) + ((j >> 3) << 4)) * 8 + (j & 7)] =
        bf16bits((j <= i) ? aa : 0.f);
  }
  __syncthreads();
  for (int i = 1; i < 32; ++i) {
    float upd = 0.f;
    if (t < i) {
      for (int kk = t + 1; kk < i; ++kk) upd += inv_s[i][kk] * inv_s[kk][t];
    }
    __syncthreads();
    if (t < i) inv_s[i][t] += upd;
    __syncthreads();
  }
  #pragma unroll
  for (int p = 0; p < 4; ++p) {
    int e = t + (p << 8);
    int i = e >> 5, j = e & 31;
    float val = inv_s[i][j] + (i == j ? 1.f : 0.f);
    val = __bfloat162float(__float2bfloat16(val));
    invb[((size_t)ci << 10) + e] = val;
  }
}

// ---------------- u = inv@(vs*beta) -> u_out; w = -(inv@(kn*beta)) as bf16 frag-order ----------------
__global__ __launch_bounds__(256) void uw_kernel(const float* __restrict__ invb,
    const float* __restrict__ vs, const float* __restrict__ kn,
    const float* __restrict__ beta,
    float* __restrict__ u_out, __hip_bfloat16* w_bf) {
  __shared__ float inv_s[32][33];
  __shared__ float tile[32][260];
  __shared__ float bt_s[32];
  int ci = blockIdx.x, t = threadIdx.x;
  size_t base = ((size_t)ci) << 13;
  int bb = ci >> 9, hh = (ci >> 7) & 3, nc = ci & 127;
  size_t vbase = (((size_t)(bb * L_ + nc * 32)) << 10) + (hh << 8);
  for (int e = t; e < 1024; e += 256) inv_s[e >> 5][e & 31] = invb[((size_t)ci << 10) + e];
  if (t < 32) bt_s[t] = beta[(((size_t)(bb * L_ + nc * 32 + t)) << 2) + hh];
  for (int ph = 0; ph < 2; ++ph) {
    __syncthreads();
    for (int f = t; f < 2048; f += 256) {
      int e = f << 2;
      int i = e >> 8, d = e & 255;
      float4 v4;
      if (ph == 0) v4 = *(const float4*)(vs + vbase + (size_t)i * 1024 + d);
      else         v4 = *(const float4*)(kn + base + (i << 8) + d);
      float bt = bt_s[i];
      v4.x *= bt; v4.y *= bt; v4.z *= bt; v4.w *= bt;
      *(float4*)&tile[i][d] = v4;
    }
    __syncthreads();
    int c4 = (t & 63) << 2;
    int ig = t >> 6;
    float4 acc[8];
    #pragma unroll
    for (int ii = 0; ii < 8; ++ii) acc[ii] = make_float4(0.f, 0.f, 0.f, 0.f);
    for (int j = 0; j < 32; ++j) {
      float4 v4 = *(const float4*)&tile[j][c4];
      #pragma unroll
      for (int ii = 0; ii < 8; ++ii) {
        float iv = inv_s[(ig << 3) + ii][j];
        acc[ii].x += iv * v4.x; acc[ii].y += iv * v4.y;
        acc[ii].z += iv * v4.z; acc[ii].w += iv * v4.w;
      }
    }
    #pragma unroll
    for (int ii = 0; ii < 8; ++ii) {
      int i = (ig << 3) + ii;
      if (ph == 0) {
        *(float4*)(u_out + base + (i << 8) + c4) = acc[ii];
      } else {
        ushort4 o;
        o.x = bf16bits(-acc[ii].x); o.y = bf16bits(-acc[ii].y);
        o.z = bf16bits(-acc[ii].z); o.w = bf16bits(-acc[ii].w);
        unsigned short* wd = (unsigned short*)w_bf + (((size_t)ci) << 14) +
            (size_t)(((i >> 4) << 3) + (c4 >> 5)) * 512 +
            (size_t)((i & 15) + (((c4 >> 3) & 3) << 4)) * 8 + (c4 & 7);
        *(ushort4*)wd = o;
      }
    }
  }
}

// ---------------- single-wave MFMA scan, register-direct operands (round-4 best) ----------------
__global__ __launch_bounds__(64, 1) void scan_kernel(
    const __hip_bfloat16* __restrict__ w_bf,
    const __hip_bfloat16* __restrict__ kq_bf,
    const __hip_bfloat16* __restrict__ att_bf,
    const float* __restrict__ u, float* __restrict__ dout) {
  __shared__ __align__(16) unsigned short Sim[2][2][16 * 264];
  __shared__ __align__(16) float UtT[16 * 36];
  int lane = threadIdx.x;
  int mlane = lane & 15, quad = lane >> 4;
  int bh = blockIdx.x & 7;
  int cb = blockIdx.x >> 3;
  int cbase = cb << 4;

  const unsigned short* wbase = (const unsigned short*)w_bf;
  const unsigned short* kqbase = (const unsigned short*)kq_bf;
  const unsigned short* abase = (const unsigned short*)att_bf;

  short8 Wr[16], Qr[16], Kr[16], Ar[2];
  float ur[8], urn[8];

  auto load_WQ = [&](int nc) {
    size_t cb14 = ((size_t)(bh * NCH_ + nc)) << 14;
    const short8* wg = (const short8*)(wbase + cb14 + (size_t)lane * 8);
    const short8* qg = (const short8*)(kqbase + cb14 + 8192 + (size_t)lane * 8);
    #pragma unroll
    for (int s = 0; s < 16; ++s) { Wr[s] = wg[s * 64]; Qr[s] = qg[s * 64]; }
  };
  auto load_K = [&](int nc) {
    size_t cb14 = ((size_t)(bh * NCH_ + nc)) << 14;
    const short8* kg = (const short8*)(kqbase + cb14 + (size_t)lane * 8);
    #pragma unroll
    for (int s = 0; s < 16; ++s) Kr[s] = kg[s * 64];
  };
  auto load_A = [&](int nc) {
    const short8* ag = (const short8*)(abase + (((size_t)(bh * NCH_ + nc)) << 10) +
                                       (size_t)lane * 8);
    Ar[0] = ag[0]; Ar[1] = ag[64];
  };
  auto load_u8 = [&](int nc, float* dst) {
    size_t cbf = ((size_t)(bh * NCH_ + nc)) << 13;
    const float* up = u + cbf + (size_t)(quad * 4) * 256 + cbase + mlane;
    #pragma unroll
    for (int tt = 0; tt < 2; ++tt)
      #pragma unroll
      for (int r = 0; r < 4; ++r) dst[tt * 4 + r] = up[(tt * 16 + r) * 256];
  };

  for (int e = lane; e < 16 * 264; e += 64) { Sim[0][0][e] = 0; Sim[0][1][e] = 0; }
  f32x4 accS[16];
  #pragma unroll
  for (int i = 0; i < 16; ++i) accS[i] = (f32x4){0.f, 0.f, 0.f, 0.f};

  load_WQ(0);
  load_K(0);
  load_A(0);
  load_u8(0, ur);

  for (int nc = 0; nc < NCH_; ++nc) {
    int cur = nc & 1, alt = cur ^ 1;
    int nn = nc + 1 < NCH_ ? nc + 1 : NCH_ - 1;

    f32x4 uh0 = (f32x4){ur[0], ur[1], ur[2], ur[3]};
    f32x4 uh1 = (f32x4){ur[4], ur[5], ur[6], ur[7]};
    f32x4 ul0 = (f32x4){0.f, 0.f, 0.f, 0.f}, ul1 = (f32x4){0.f, 0.f, 0.f, 0.f};
    f32x4 oh0 = (f32x4){0.f, 0.f, 0.f, 0.f}, oh1 = (f32x4){0.f, 0.f, 0.f, 0.f};
    f32x4 ol0 = (f32x4){0.f, 0.f, 0.f, 0.f}, ol1 = (f32x4){0.f, 0.f, 0.f, 0.f};
    #pragma unroll
    for (int kt = 0; kt < 8; ++kt) {
      short8 bhi = *(const short8*)&Sim[cur][0][mlane * 264 + kt * 32 + quad * 8];
      short8 blo = *(const short8*)&Sim[cur][1][mlane * 264 + kt * 32 + quad * 8];
      uh0 = __builtin_amdgcn_mfma_f32_16x16x32_bf16(Wr[kt], bhi, uh0, 0, 0, 0);
      ul0 = __builtin_amdgcn_mfma_f32_16x16x32_bf16(Wr[kt], blo, ul0, 0, 0, 0);
      uh1 = __builtin_amdgcn_mfma_f32_16x16x32_bf16(Wr[8 + kt], bhi, uh1, 0, 0, 0);
      ul1 = __builtin_amdgcn_mfma_f32_16x16x32_bf16(Wr[8 + kt], blo, ul1, 0, 0, 0);
      oh0 = __builtin_amdgcn_mfma_f32_16x16x32_bf16(Qr[kt], bhi, oh0, 0, 0, 0);
      ol0 = __builtin_amdgcn_mfma_f32_16x16x32_bf16(Qr[kt], blo, ol0, 0, 0, 0);
      oh1 = __builtin_amdgcn_mfma_f32_16x16x32_bf16(Qr[8 + kt], bhi, oh1, 0, 0, 0);
      ol1 = __builtin_amdgcn_mfma_f32_16x16x32_bf16(Qr[8 + kt], blo, ol1, 0, 0, 0);
    }
    f32x4 ut0 = uh0 + ul0, ut1 = uh1 + ul1;
    *(f32x4*)&UtT[mlane * 36 + quad * 4] = ut0;
    *(f32x4*)&UtT[mlane * 36 + 16 + quad * 4] = ut1;
    load_WQ(nn);
    load_u8(nn, urn);
    short8 but;
    {
      const float* up = &UtT[mlane * 36 + quad * 8];
      #pragma unroll
      for (int j = 0; j < 8; ++j) but[j] = (short)bf16bits(up[j]);
    }
    f32x4 o0 = oh0 + ol0, o1 = oh1 + ol1;
    o0 = __builtin_amdgcn_mfma_f32_16x16x32_bf16(Ar[0], but, o0, 0, 0, 0);
    o1 = __builtin_amdgcn_mfma_f32_16x16x32_bf16(Ar[1], but, o1, 0, 0, 0);
    load_A(nn);
    size_t cbf = ((size_t)(bh * NCH_ + nc)) << 13;
    float* op = dout + cbf + (size_t)(quad * 4) * 256 + cbase + mlane;
    #pragma unroll
    for (int r = 0; r < 4; ++r) { op[r * 256] = o0[r]; op[(16 + r) * 256] = o1[r]; }
    #pragma unroll
    for (int t2 = 0; t2 < 16; ++t2) {
      accS[t2] = __builtin_amdgcn_mfma_f32_16x16x32_bf16(Kr[t2], but, accS[t2], 0, 0, 0);
      unsigned short nh[4], nl[4];
      #pragma unroll
      for (int r = 0; r < 4; ++r) {
        float sv = accS[t2][r];
        unsigned short hb = bf16bits(sv);
        nh[r] = hb;
        nl[r] = bf16bits(sv - bits2f(hb));
      }
      *(uint2*)&Sim[alt][0][mlane * 264 + t2 * 16 + quad * 4] = *(const uint2*)nh;
      *(uint2*)&Sim[alt][1][mlane * 264 + t2 * 16 + quad * 4] = *(const uint2*)nl;
    }
    load_K(nn);
    #pragma unroll
    for (int r = 0; r < 8; ++r) ur[r] = urn[r];
  }
}

// ---------------- gate: NL=8 tokens/block; shared qg-matvec hoisted to qgH GEMM ----------------
__global__ __launch_bounds__(256, 1) void gate_kernel(
    const float* __restrict__ v, const float* __restrict__ delta,
    const float* __restrict__ qgH,
    const float* __restrict__ fw0, const float* __restrict__ fw1T,
    const float* __restrict__ fw2T, const float* __restrict__ fw3T,
    const float* __restrict__ Wf1, const float* __restrict__ Wf2,
    const float* __restrict__ bf1, const float* __restrict__ bf2,
    const float* __restrict__ ltm, const float* __restrict__ onw,
    __hip_bfloat16* __restrict__ obf) {
  __shared__ float W1t[6][136];   // Wf1 rows 128..133 (summary tail)
  __shared__ float W2f[804];      // Wf2 [134][6] flat
  __shared__ float bf1s[136];
  int t = threadIdx.x;
  int wave = t >> 6, lane = t & 63;
  for (int e = t; e < 804; e += 256) {
    int s = e / 134, u = e - s * 134;
    W1t[s][u] = Wf1[(128 + s) * GH_c + u];
    W2f[e] = Wf2[e];
  }
  if (t < GH_c) bf1s[t] = bf1[t];
  __syncthreads();

  int bid = blockIdx.x;
  int bl0 = (((bid & 7) << 7) | (bid >> 3)) << 3;   // 1024 blocks -> 8 tokens each
  int b = bl0 >> 12;
  int h = wave;
  int c = (h << 8) + (lane << 2);

  float4 fw3r[15], fw2r[7], fw1r[3], fw0r;
  #pragma unroll
  for (int j = 0; j < 15; ++j) fw3r[j] = *(const float4*)(fw3T + (j << 10) + c);
  #pragma unroll
  for (int j = 0; j < 7; ++j) fw2r[j] = *(const float4*)(fw2T + (j << 10) + c);
  #pragma unroll
  for (int j = 0; j < 3; ++j) fw1r[j] = *(const float4*)(fw1T + (j << 10) + c);
  fw0r = *(const float4*)(fw0 + c);
  float4 ow = *(const float4*)(onw + (lane << 2));
  float itemp = expf(ltm[h]);
  float b2r[6];
  #pragma unroll
  for (int s = 0; s < 6; ++s) b2r[s] = bf2[s];
  int u3 = 128 + (lane < 6 ? lane : 0);

  auto gelu = [](float a) -> float {
    return 0.5f * a * (1.f + erff(a * 0.70710678f));
  };

  for (int tk = 0; tk < 8; ++tk) {
    int bl = bl0 + tk;
    int l = bl & (L_ - 1);
    float4 st0, st1, st2, st3, st4, st5;
    st1 = make_float4(0, 0, 0, 0);
    st2 = make_float4(0, 0, 0, 0);
    st3 = make_float4(0, 0, 0, 0);
    #pragma unroll
    for (int j = 0; j < 15; ++j) {
      int ll = l - 14 + j;
      float4 vj = make_float4(0, 0, 0, 0);
      if (ll >= 0) vj = *(const float4*)(v + ((((size_t)(b * L_ + ll)) << 10) + c));
      st3 = fma4(fw3r[j], vj, st3);
      if (j >= 8) st2 = fma4(fw2r[j - 8], vj, st2);
      if (j >= 12) st1 = fma4(fw1r[j - 12], vj, st1);
      if (j == 14) {
        st0 = make_float4(fw0r.x * vj.x, fw0r.y * vj.y, fw0r.z * vj.z, fw0r.w * vj.w);
        st5 = vj;
      }
    }
    st4 = *(const float4*)(delta + ((((size_t)((b * H_ + h) * L_ + l)) << 8) + (lane << 2)));

    float s0 = st0.x + st0.y + st0.z + st0.w;
    float s1 = st1.x + st1.y + st1.z + st1.w;
    float s2 = st2.x + st2.y + st2.z + st2.w;
    float s3 = st3.x + st3.y + st3.z + st3.w;
    float s4 = st4.x + st4.y + st4.z + st4.w;
    float s5 = st5.x + st5.y + st5.z + st5.w;
    #pragma unroll
    for (int o = 32; o > 0; o >>= 1) {
      s0 += __shfl_down(s0, o, 64); s1 += __shfl_down(s1, o, 64);
      s2 += __shfl_down(s2, o, 64); s3 += __shfl_down(s3, o, 64);
      s4 += __shfl_down(s4, o, 64); s5 += __shfl_down(s5, o, 64);
    }
    float ss_[6];
    ss_[0] = __shfl(s0, 0, 64) * (1.f / 256.f);
    ss_[1] = __shfl(s1, 0, 64) * (1.f / 256.f);
    ss_[2] = __shfl(s2, 0, 64) * (1.f / 256.f);
    ss_[3] = __shfl(s3, 0, 64) * (1.f / 256.f);
    ss_[4] = __shfl(s4, 0, 64) * (1.f / 256.f);
    ss_[5] = __shfl(s5, 0, 64) * (1.f / 256.f);

    const float* qr = qgH + ((size_t)bl << 8);
    float a0 = qr[lane] + bf1s[lane];
    float a1 = qr[64 + lane] + bf1s[64 + lane];
    float a2 = qr[u3] + bf1s[u3];
    #pragma unroll
    for (int s = 0; s < 6; ++s) {
      a0 = fmaf(W1t[s][lane], ss_[s], a0);
      a1 = fmaf(W1t[s][64 + lane], ss_[s], a1);
      a2 = fmaf(W1t[s][u3], ss_[s], a2);
    }
    float h0 = gelu(a0);
    float h1 = gelu(a1);
    float h2 = (lane < 6) ? gelu(a2) : 0.f;

    const float* w2a = W2f + lane * 6;
    const float* w2b = W2f + (64 + lane) * 6;
    const float* w2c = W2f + u3 * 6;
    float t0 = h0 * w2a[0] + h1 * w2b[0] + h2 * w2c[0];
    float t1 = h0 * w2a[1] + h1 * w2b[1] + h2 * w2c[1];
    float t2 = h0 * w2a[2] + h1 * w2b[2] + h2 * w2c[2];
    float t3 = h0 * w2a[3] + h1 * w2b[3] + h2 * w2c[3];
    float t4 = h0 * w2a[4] + h1 * w2b[4] + h2 * w2c[4];
    float t5 = h0 * w2a[5] + h1 * w2b[5] + h2 * w2c[5];
    #pragma unroll
    for (int o = 32; o > 0; o >>= 1) {
      t0 += __shfl_down(t0, o, 64); t1 += __shfl_down(t1, o, 64);
      t2 += __shfl_down(t2, o, 64); t3 += __shfl_down(t3, o, 64);
      t4 += __shfl_down(t4, o, 64); t5 += __shfl_down(t5, o, 64);
    }
    float p0, p1, p2, p3, p4, p5;
    if (lane == 0) {
      float l0v = (t0 + b2r[0]) / itemp, l1v = (t1 + b2r[1]) / itemp;
      float l2v = (t2 + b2r[2]) / itemp, l3v = (t3 + b2r[3]) / itemp;
      float l4v = (t4 + b2r[4]) / itemp, l5v = (t5 + b2r[5]) / itemp;
      float m = fmaxf(fmaxf(fmaxf(l0v, l1v), fmaxf(l2v, l3v)), fmaxf(l4v, l5v));
      float e0 = expf(l0v - m), e1 = expf(l1v - m), e2 = expf(l2v - m);
      float e3 = expf(l3v - m), e4 = expf(l4v - m), e5 = expf(l5v - m);
      float inv = 1.f / (e0 + e1 + e2 + e3 + e4 + e5);
      p0 = e0 * inv * 0.88f + 0.02f; p1 = e1 * inv * 0.88f + 0.02f;
      p2 = e2 * inv * 0.88f + 0.02f; p3 = e3 * inv * 0.88f + 0.02f;
      p4 = e4 * inv * 0.88f + 0.02f; p5 = e5 * inv * 0.88f + 0.02f;
    }
    p0 = __shfl(p0, 0, 64); p1 = __shfl(p1, 0, 64); p2 = __shfl(p2, 0, 64);
    p3 = __shfl(p3, 0, 64); p4 = __shfl(p4, 0, 64); p5 = __shfl(p5, 0, 64);

    float4 fu;
    fu.x = p0 * st0.x + p1 * st1.x + p2 * st2.x + p3 * st3.x + p4 * st4.x + p5 * st5.x;
    fu.y = p0 * st0.y + p1 * st1.y + p2 * st2.y + p3 * st3.y + p4 * st4.y + p5 * st5.y;
    fu.z = p0 * st0.z + p1 * st1.z + p2 * st2.z + p3 * st3.z + p4 * st4.z + p5 * st5.z;
    fu.w = p0 * st0.w + p1 * st1.w + p2 * st2.w + p3 * st3.w + p4 * st4.w + p5 * st5.w;
    float ssq = fu.x * fu.x + fu.y * fu.y + fu.z * fu.z + fu.w * fu.w;
    #pragma unroll
    for (int o = 32; o > 0; o >>= 1) ssq += __shfl_xor(ssq, o, 64);
    float sc = rsqrtf(ssq * (1.f / 256.f) + 1e-5f);
    ushort4 ob;
    ob.x = bf16bits(fu.x * sc * ow.x);
    ob.y = bf16bits(fu.y * sc * ow.y);
    ob.z = bf16bits(fu.z * sc * ow.z);
    ob.w = bf16bits(fu.w * sc * ow.w);
    *(ushort4*)((unsigned short*)obf + (((size_t)bl) << 10) + c) = ob;
  }
}

// ---------------- launch ----------------
extern "C" void kernel_launch(void* const* d_in, const int* in_sizes, int n_in,
                              void* d_out, int out_size, void* d_ws, size_t ws_size,
                              hipStream_t stream) {
  const float* x   = (const float*)d_in[0];
  const float* Wq  = (const float*)d_in[1];
  const float* Wk  = (const float*)d_in[2];
  const float* Wv  = (const float*)d_in[3];
  const float* Wb  = (const float*)d_in[4];
  const float* cqw = (const float*)d_in[5];
  const float* ckw = (const float*)d_in[6];
  const float* cvw = (const float*)d_in[7];
  const float* fw0 = (const float*)d_in[8];
  const float* fw1 = (const float*)d_in[9];
  const float* fw2 = (const float*)d_in[10];
  const float* fw3 = (const float*)d_in[11];
  const float* Wqg = (const float*)d_in[12];
  const float* bqg = (const float*)d_in[13];
  const float* Wf1 = (const float*)d_in[14];
  const float* bf1 = (const float*)d_in[15];
  const float* Wf2 = (const float*)d_in[16];
  const float* bf2 = (const float*)d_in[17];
  const float* ltm = (const float*)d_in[18];
  const float* onw = (const float*)d_in[19];
  const float* Wo  = (const float*)d_in[20];
  float* out = (float*)d_out;
  float* ws = (float*)d_ws;

  const size_t BIG = (size_t)BL_ * C_;
  float* qpre = ws;                 // GEMM q out -> gate_bf after gate
  float* kpre = ws + BIG;           // GEMM k out -> knT_bf+qn_bf (frag-order)
  float* vpre = ws + 2 * BIG;       // GEMM v out -> u f32 (uw output)
  float* qs   = ws + 3 * BIG;       // x_bf early -> qn f32 -> delta_out (scan)
  float* ks   = ws + 4 * BIG;       // kn f32 -> qgH/qg_bf/wf1qT after uw
  float* vs   = ws + 5 * BIG;       // v_direct (fused conv out, gate FIR input)
  float* kbw  = ws + 6 * BIG;       // wT bf16 early -> w_bf (frag-order) -> woT
  float* invb = ws + 7 * BIG;
  float* attb = invb + (size_t)1024 * 1024;
  float* beta = attb + (size_t)1024 * 1024;
  float* qg   = beta + (size_t)BL_ * H_;

  __hip_bfloat16* x_bf  = (__hip_bfloat16*)qs;
  __hip_bfloat16* wqT   = (__hip_bfloat16*)kbw;
  __hip_bfloat16* wkT   = wqT + (size_t)1024 * 1024;
  __hip_bfloat16* wvT   = wkT + (size_t)1024 * 1024;
  __hip_bfloat16* wqgT  = wvT + (size_t)1024 * 1024;
  __hip_bfloat16* woT   = (__hip_bfloat16*)kbw;
  __hip_bfloat16* gate_bf = (__hip_bfloat16*)qpre;
  __hip_bfloat16* knT_bf = (__hip_bfloat16*)kpre;   // + qn_bf in slot second halves
  __hip_bfloat16* w_bf   = (__hip_bfloat16*)kbw;
  __hip_bfloat16* att_bf = (__hip_bfloat16*)attb;
  float* scr   = attb + (size_t)600000;
  float* fw1T  = scr;
  float* fw2T  = scr + 3072;
  float* fw3T  = scr + 10240;
  float* cqwT  = scr + 25600;       // [4][1024] transposed conv weights
  float* ckwT  = scr + 29696;
  float* cvwT  = scr + 33792;

  float* qgH = ks;                                            // 8192 x 256 f32 (after uw)
  __hip_bfloat16* qg_bf  = (__hip_bfloat16*)(ks + (size_t)3 * 1024 * 1024);
  __hip_bfloat16* wf1qT  = (__hip_bfloat16*)(ks + (size_t)4 * 1024 * 1024);

  dim3 blk(256);
  f32_to_bf16_k<<<dim3(BL_ * D_ / 1024), blk, 0, stream>>>(x, x_bf);
  transpose_bf16<<<dim3(32, 32), blk, 0, stream>>>(Wq, wqT, D_, C_);
  transpose_bf16<<<dim3(32, 32), blk, 0, stream>>>(Wk, wkT, D_, C_);
  transpose_bf16<<<dim3(32, 32), blk, 0, stream>>>(Wv, wvT, D_, C_);
  transpose_bf16<<<dim3(4, 32), blk, 0, stream>>>(Wqg, wqgT, D_, GQP_c);
  small_transpose<<<dim3(16), blk, 0, stream>>>(fw1, fw1T, 1024, 3, 1024);
  small_transpose<<<dim3(32), blk, 0, stream>>>(fw2, fw2T, 1024, 7, 1024);
  small_transpose<<<dim3(64), blk, 0, stream>>>(fw3, fw3T, 1024, 15, 1024);
  conv_prep<<<dim3(16), blk, 0, stream>>>(cqw, cqwT);
  conv_prep<<<dim3(16), blk, 0, stream>>>(ckw, ckwT);
  conv_prep<<<dim3(16), blk, 0, stream>>>(cvw, cvwT);
  gemm_bf16<<<dim3(8, 64), blk, 0, stream>>>(x_bf, wqT, nullptr, qpre, BL_, C_, D_);
  gemm_bf16<<<dim3(8, 64), blk, 0, stream>>>(x_bf, wkT, nullptr, kpre, BL_, C_, D_);
  gemm_bf16<<<dim3(8, 64), blk, 0, stream>>>(x_bf, wvT, nullptr, vpre, BL_, C_, D_);
  gemm_bf16<<<dim3(1, 64), blk, 0, stream>>>(x_bf, wqgT, bqg, qg, BL_, GQP_c, D_);
  beta_kernel<<<dim3(BL_), blk, 0, stream>>>(x, Wb, beta);
  // fused conv+silu+l2norm+transpose (overwrites x_bf in qs with qn; writes kn->ks, vs)
  conv_norm_fused<<<dim3(BL_), blk, 0, stream>>>(qpre, kpre, vpre, cqwT, ckwT, cvwT,
                                                 vs, qs, ks);
  inv_attn<<<dim3(1024), blk, 0, stream>>>(qs, ks, beta, invb, att_bf, knT_bf);
  uw_kernel<<<dim3(1024), blk, 0, stream>>>(invb, vs, ks, beta, vpre, w_bf);
  // ks slot now free: build qgH = qg @ Wf1[0:128,:] (bf16 MFMA, f32 accum)
  f32_to_bf16_k<<<dim3(BL_ * GQP_c / 1024), blk, 0, stream>>>(qg, qg_bf);
  wf1q_prep<<<dim3(128), blk, 0, stream>>>(Wf1, wf1qT);
  gemm_bf16<<<dim3(2, 64), blk, 0, stream>>>(qg_bf, wf1qT, nullptr, qgH, BL_, 256, 128);
  scan_kernel<<<dim3(128), dim3(64), 0, stream>>>(w_bf, knT_bf, att_bf, vpre, qs);
  transpose_bf16<<<dim3(32, 32), blk, 0, stream>>>(Wo, woT, C_, D_);
  gate_kernel<<<dim3(1024), blk, 0, stream>>>(vs, qs, qgH, fw0, fw1T, fw2T, fw3T,
                                              Wf1, Wf2, bf1, bf2, ltm, onw, gate_bf);
  gemm_bf16<<<dim3(8, 64), blk, 0, stream>>>(gate_bf, woT, nullptr, out, BL_, D_, C_);
}